// Round 16
// baseline (181.122 us; speedup 1.0000x reference)
//
#include <hip/hip_runtime.h>
#include <math.h>

#define N_NODES 50000
#define N_EDGES 800000
#define ETOT (N_EDGES + N_NODES)
#define NG 64
#define NBUCK 196                 // dst buckets of 256 nodes
#define CHUNK 4096
#define NCHUNK ((ETOT + CHUNK - 1)/CHUNK)   // 208
#define SCANN (NBUCK*NCHUNK)      // 40768
#define GSB ((SCANN + 255)/256)   // 160
#define GB1 ((N_NODES + 63)/64)   // 782 gemm1 blocks

typedef float vf2 __attribute__((ext_vector_type(2)));
typedef short bf16x8 __attribute__((ext_vector_type(8)));
typedef float f32x4 __attribute__((ext_vector_type(4)));

__device__ __forceinline__ float leaky02(float a){ return a > 0.f ? a : 0.2f*a; }
__device__ __forceinline__ float eluf(float v){ return v > 0.f ? v : expm1f(v); }

// round-to-nearest-even f32->bf16, packed pair (a low, b high)
__device__ __forceinline__ unsigned pack_bf16(float a, float b){
  unsigned ua = __float_as_uint(a); ua += 0x7fffu + ((ua >> 16) & 1u);
  unsigned ub = __float_as_uint(b); ub += 0x7fffu + ((ub >> 16) & 1u);
  return (ua >> 16) | (ub & 0xffff0000u);
}
__device__ __forceinline__ float bf_lo(unsigned v){ return __uint_as_float(v << 16); }
__device__ __forceinline__ float bf_hi(unsigned v){ return __uint_as_float(v & 0xffff0000u); }

// fp8 e4m3 pack via HW cvt (self-consistent internal format)
__device__ __forceinline__ unsigned pack_fp8x4(float4 a){
  int v = __builtin_amdgcn_cvt_pk_fp8_f32(a.x, a.y, 0, false);
  v = __builtin_amdgcn_cvt_pk_fp8_f32(a.z, a.w, v, true);
  return (unsigned)v;
}

// ---------------- hist (+ fused weight prep in extra blocks) ---------------------------
__global__ __launch_bounds__(256) void k_hist(const int* __restrict__ ei,
    unsigned* __restrict__ cnt, const float* __restrict__ W1, const float* __restrict__ W2,
    unsigned* __restrict__ wt1, unsigned* __restrict__ wt2){
  if (blockIdx.x >= NCHUNK){
    int b = blockIdx.x - NCHUNK;   // 0..159
    int t = threadIdx.x;
    if (t < 64){
      if (b < 128){
        float a = W1[(size_t)(2*t)*128 + b];
        float c = W1[(size_t)(2*t+1)*128 + b];
        wt1[b*64 + t] = pack_bf16(a, c);
      } else {
        int cc = b - 128;
        float a = W2[(size_t)(2*t)*32 + cc];
        float c = W2[(size_t)(2*t+1)*32 + cc];
        wt2[cc*64 + t] = pack_bf16(a, c);
      }
    }
    return;
  }
  __shared__ unsigned hist[NBUCK];
  int tid = threadIdx.x;
  for (int t = tid; t < NBUCK; t += 256) hist[t] = 0;
  __syncthreads();
  int base = blockIdx.x * CHUNK;
  #pragma unroll
  for (int i = 0; i < CHUNK/256; ++i){
    int e = base + i*256 + tid;
    if (e < ETOT){
      int d = (e < N_EDGES) ? ei[N_EDGES + e] : (e - N_EDGES);
      atomicAdd(&hist[d >> 8], 1u);
    }
  }
  __syncthreads();
  for (int t = tid; t < NBUCK; t += 256) cnt[t*NCHUNK + blockIdx.x] = hist[t];
}

// ---------------- merged exclusive scan: base-sum of predecessors + local scan ---------
__global__ __launch_bounds__(256) void g_scanM(const unsigned* __restrict__ in,
    unsigned* __restrict__ out, int n){
  __shared__ unsigned red[4];
  __shared__ unsigned ts[256];
  int t = threadIdx.x, blk = blockIdx.x, i = blk*256 + t;
  unsigned s = 0;
  for (int j = t; j < blk*256; j += 256) s += in[j];
  #pragma unroll
  for (int o = 32; o >= 1; o >>= 1) s += __shfl_xor(s, o);
  if ((t & 63) == 0) red[t >> 6] = s;
  unsigned v = (i < n) ? in[i] : 0u;
  ts[t] = v;
  __syncthreads();
  unsigned base = red[0] + red[1] + red[2] + red[3];
  for (int o = 1; o < 256; o <<= 1){
    unsigned u = (t >= o) ? ts[t-o] : 0u;
    __syncthreads();
    ts[t] += u;
    __syncthreads();
  }
  if (i < n) out[i] = base + ts[t] - v;
}

// ---------------- fused: edge partition (208 blocks) || GEMM1 (782 blocks) -------------
__global__ __launch_bounds__(256) void k_pg(const int* __restrict__ ei,
    const unsigned* __restrict__ basev, unsigned* __restrict__ staging,
    const float* __restrict__ x, const unsigned* __restrict__ wt1,
    const float* __restrict__ attS, const float* __restrict__ attD,
    unsigned* __restrict__ h1f, float* __restrict__ asrc, float* __restrict__ adst)
{
  __shared__ unsigned cur[NBUCK];
  __shared__ __align__(16) short xs[64*136];    // 17.4 KB bf16
  __shared__ __align__(16) short wb[128*136];   // 34.8 KB bf16; reused as Cst f32 [64][132]
  int tid = threadIdx.x;

  if (blockIdx.x < NCHUNK){
    // ---- edge partition ----
    for (int t = tid; t < NBUCK; t += 256) cur[t] = basev[t*NCHUNK + blockIdx.x];
    __syncthreads();
    int base = blockIdx.x * CHUNK;
    #pragma unroll
    for (int i = 0; i < CHUNK/256; ++i){
      int e = base + i*256 + tid;
      if (e < ETOT){
        int s, d;
        if (e < N_EDGES){ s = ei[e]; d = ei[N_EDGES + e]; } else { s = d = e - N_EDGES; }
        unsigned pos = atomicAdd(&cur[d >> 8], 1u);
        staging[pos] = (unsigned)s | ((unsigned)(d & 255) << 16);
      }
    }
    return;
  }

  // ---- GEMM1 (MFMA bf16): h1 = x @ W1 -> fp8; alphas from f32 acc ----
  float* Cst = (float*)wb;
  int base = (blockIdx.x - NCHUNK) * 64;
  {
    int row = tid >> 2, q = tid & 3;
    const float* src = x + (size_t)(base + row)*128 + q*32;
    bool valid = (base + row) < N_NODES;
    #pragma unroll
    for (int i = 0; i < 8; ++i){
      float4 v = valid ? *(const float4*)(src + 4*i) : make_float4(0,0,0,0);
      *(uint2*)(&xs[row*136 + q*32 + 4*i]) = make_uint2(pack_bf16(v.x, v.y), pack_bf16(v.z, v.w));
    }
  }
  {
    int c = tid >> 1, h = tid & 1;
    #pragma unroll
    for (int i = 0; i < 8; ++i){
      uint4 v = *(const uint4*)(wt1 + c*64 + h*32 + 4*i);
      *(uint4*)(&wb[c*136 + h*64 + 8*i]) = v;
    }
  }
  __syncthreads();
  int lane = tid & 63, wid = tid >> 6;
  int r = lane & 15, g = lane >> 4;
  bf16x8 afr[4];
  #pragma unroll
  for (int kk = 0; kk < 4; ++kk)
    afr[kk] = *(const bf16x8*)(&xs[(wid*16 + r)*136 + kk*32 + g*8]);
  f32x4 acc[8];
  #pragma unroll
  for (int ct = 0; ct < 8; ++ct){ acc[ct][0]=0.f; acc[ct][1]=0.f; acc[ct][2]=0.f; acc[ct][3]=0.f; }
  #pragma unroll
  for (int ct = 0; ct < 8; ++ct){
    #pragma unroll
    for (int kk = 0; kk < 4; ++kk){
      bf16x8 bfr = *(const bf16x8*)(&wb[(ct*16 + r)*136 + kk*32 + g*8]);
      acc[ct] = __builtin_amdgcn_mfma_f32_16x16x32_bf16(afr[kk], bfr, acc[ct], 0, 0, 0);
    }
  }
  __syncthreads();   // everyone done reading wb; reuse as Cst
  #pragma unroll
  for (int ct = 0; ct < 8; ++ct){
    #pragma unroll
    for (int q = 0; q < 4; ++q)
      Cst[(wid*16 + 4*g + q)*132 + ct*16 + r] = acc[ct][q];
  }
  __syncthreads();
  {
    int row = tid >> 2, hd = tid & 3;
    int grow = base + row;
    if (grow < N_NODES){
      const float* cp = &Cst[row*132 + hd*32];
      const float* aS = attS + hd*32;
      const float* aD = attD + hd*32;
      float ps = 0.f, pd = 0.f;
      unsigned u[8];
      #pragma unroll
      for (int i = 0; i < 8; ++i){
        float4 c4 = *(const float4*)(cp + 4*i);
        ps += c4.x*aS[4*i] + c4.y*aS[4*i+1] + c4.z*aS[4*i+2] + c4.w*aS[4*i+3];
        pd += c4.x*aD[4*i] + c4.y*aD[4*i+1] + c4.z*aD[4*i+2] + c4.w*aD[4*i+3];
        u[i] = pack_fp8x4(c4);
      }
      unsigned* dst = h1f + (size_t)grow*32 + hd*8;
      *(uint4*)(dst)     = make_uint4(u[0], u[1], u[2], u[3]);
      *(uint4*)(dst + 4) = make_uint4(u[4], u[5], u[6], u[7]);
      asrc[grow*4 + hd] = ps;
      adst[grow*4 + hd] = pd;
    }
  }
}

__global__ __launch_bounds__(256) void k_csr(const unsigned* __restrict__ basev,
    const unsigned* __restrict__ staging, unsigned* __restrict__ off,
    int* __restrict__ csr_src){
  __shared__ unsigned ts[256], cur[256];
  int tid = threadIdx.x, b = blockIdx.x;
  unsigned start = basev[b*NCHUNK];
  unsigned end = (b == NBUCK-1) ? (unsigned)ETOT : basev[(b+1)*NCHUNK];
  ts[tid] = 0;
  __syncthreads();
  for (unsigned i = start + tid; i < end; i += 256)
    atomicAdd(&ts[staging[i] >> 16], 1u);
  __syncthreads();
  unsigned v = ts[tid];
  for (int o = 1; o < 256; o <<= 1){
    unsigned u = (tid >= o) ? ts[tid-o] : 0u;
    __syncthreads();
    ts[tid] += u;
    __syncthreads();
  }
  unsigned excl = ts[tid] - v;
  int node = (b << 8) + tid;
  if (node < N_NODES) off[node] = start + excl;
  if (b == 0 && tid == 0) off[N_NODES] = (unsigned)ETOT;
  cur[tid] = excl;
  __syncthreads();
  for (unsigned i = start + tid; i < end; i += 256){
    unsigned p = staging[i];
    unsigned pos = atomicAdd(&cur[p >> 16], 1u);
    csr_src[start + pos] = (int)(p & 0xffffu);
  }
}

// ---------------- conv1: wave/node; fp8 rows, no max-subtraction -----------------------
__global__ __launch_bounds__(256) void k_conv1(const unsigned* __restrict__ off,
    const int* __restrict__ csr_src, const unsigned* __restrict__ h1f,
    const float* __restrict__ asrc, const float* __restrict__ adst,
    const float* __restrict__ b1, unsigned* __restrict__ helu_b)
{
  __shared__ uint2 st[4][4][66];  // [wave][head][edge] = {exp_bits, row_byte_off}
  int w    = threadIdx.x >> 6;
  int lane = threadIdx.x & 63;
  int n = blockIdx.x*4 + w;
  if (n >= N_NODES) return;
  unsigned s0 = off[n];
  int deg = (int)(off[n+1] - s0);
  float4 ad = *(const float4*)(adst + (size_t)n*4);
  int cl = lane & 31;             // feature slot: features 4*cl..4*cl+3
  int h  = cl >> 3;               // head of this slot
  const char* hbase = (const char*)h1f + 4*cl;
  float4 acc = make_float4(0,0,0,0);
  float den = 0.f;

  if (deg <= 64){
    unsigned boff = 0;
    float e0=0.f, e1=0.f, e2=0.f, e3=0.f;
    if (lane < deg){
      int idx = csr_src[s0 + lane];
      boff = ((unsigned)idx) << 7;          // 128 B fp8 row
      float4 as = *(const float4*)(asrc + (size_t)idx*4);
      e0 = __expf(leaky02(as.x + ad.x));
      e1 = __expf(leaky02(as.y + ad.y));
      e2 = __expf(leaky02(as.z + ad.z));
      e3 = __expf(leaky02(as.w + ad.w));
    }
    st[w][0][lane] = make_uint2(__float_as_uint(e0), boff);
    st[w][1][lane] = make_uint2(__float_as_uint(e1), boff);
    st[w][2][lane] = make_uint2(__float_as_uint(e2), boff);
    st[w][3][lane] = make_uint2(__float_as_uint(e3), boff);
    __builtin_amdgcn_wave_barrier();        // wave-coherent LDS, no s_barrier
    int half = lane >> 5;
    const uint2* sp = &st[w][h][half];
    #pragma unroll 8
    for (int i = 0; i < deg; i += 2){
      uint2 p = sp[i];
      float es = __uint_as_float(p.x);
      unsigned hb = *(const unsigned*)(hbase + p.y);
      vf2 p0 = __builtin_amdgcn_cvt_pk_f32_fp8((int)hb, false);
      vf2 p1 = __builtin_amdgcn_cvt_pk_f32_fp8((int)hb, true);
      acc.x += es*p0[0]; acc.y += es*p0[1];
      acc.z += es*p1[0]; acc.w += es*p1[1];
      den += es;
    }
    acc.x += __shfl_xor(acc.x, 32); acc.y += __shfl_xor(acc.y, 32);
    acc.z += __shfl_xor(acc.z, 32); acc.w += __shfl_xor(acc.w, 32);
    den   += __shfl_xor(den, 32);
  } else {
    float adh = (h==0) ? ad.x : (h==1) ? ad.y : (h==2) ? ad.z : ad.w;
    for (int i = 0; i < deg; ++i){
      int s = csr_src[s0 + i];
      float ev = __expf(leaky02(asrc[s*4 + h] + adh));
      unsigned hb = *(const unsigned*)(hbase + (((unsigned)s) << 7));
      vf2 p0 = __builtin_amdgcn_cvt_pk_f32_fp8((int)hb, false);
      vf2 p1 = __builtin_amdgcn_cvt_pk_f32_fp8((int)hb, true);
      acc.x += ev*p0[0]; acc.y += ev*p0[1];
      acc.z += ev*p1[0]; acc.w += ev*p1[1];
      den += ev;
    }
  }
  if (lane < 32){
    float inv = 1.f/(den + 1e-16f);
    float4 bv = ((const float4*)b1)[cl];
    float ox = eluf(acc.x*inv + bv.x), oy = eluf(acc.y*inv + bv.y);
    float oz = eluf(acc.z*inv + bv.z), ow = eluf(acc.w*inv + bv.w);
    *(uint2*)(helu_b + (size_t)n*64 + 2*cl) = make_uint2(pack_bf16(ox, oy), pack_bf16(oz, ow));
  }
}

// ---------------- GEMM2 (MFMA bf16): h2 = helu @ W2, h2 -> bf16; scalar alphas ---------
__global__ __launch_bounds__(256) void k_gemm2(const unsigned* __restrict__ helu_b,
    const unsigned* __restrict__ wt2, const float* __restrict__ attS,
    const float* __restrict__ attD, unsigned* __restrict__ h2b,
    float* __restrict__ asrc, float* __restrict__ adst)
{
  __shared__ __align__(16) short xs[64*136];    // 17.4 KB
  __shared__ __align__(16) float cbuf[64*36];   // 9.2 KB f32; first 8.7 KB doubles as Wt2
  short* w2 = (short*)cbuf;
  int tid = threadIdx.x;
  int base = blockIdx.x * 64;
  {
    int row = tid >> 2, q = tid & 3;
    bool valid = (base + row) < N_NODES;
    const unsigned* src = helu_b + (size_t)(base + row)*64 + q*16;
    #pragma unroll
    for (int i = 0; i < 4; ++i){
      uint4 v = valid ? *(const uint4*)(src + 4*i) : make_uint4(0,0,0,0);
      *(uint4*)(&xs[row*136 + q*32 + 8*i]) = v;
    }
  }
  {
    int c = tid >> 3, h = tid & 7;
    uint4 v0 = *(const uint4*)(wt2 + c*64 + h*8);
    uint4 v1 = *(const uint4*)(wt2 + c*64 + h*8 + 4);
    *(uint4*)(&w2[c*136 + h*16])     = v0;
    *(uint4*)(&w2[c*136 + h*16 + 8]) = v1;
  }
  __syncthreads();
  int lane = tid & 63, wid = tid >> 6;
  int r = lane & 15, g = lane >> 4;
  bf16x8 afr[4];
  #pragma unroll
  for (int kk = 0; kk < 4; ++kk)
    afr[kk] = *(const bf16x8*)(&xs[(wid*16 + r)*136 + kk*32 + g*8]);
  f32x4 acc[2];
  #pragma unroll
  for (int ct = 0; ct < 2; ++ct){ acc[ct][0]=0.f; acc[ct][1]=0.f; acc[ct][2]=0.f; acc[ct][3]=0.f; }
  #pragma unroll
  for (int ct = 0; ct < 2; ++ct){
    #pragma unroll
    for (int kk = 0; kk < 4; ++kk){
      bf16x8 bfr = *(const bf16x8*)(&w2[(ct*16 + r)*136 + kk*32 + g*8]);
      acc[ct] = __builtin_amdgcn_mfma_f32_16x16x32_bf16(afr[kk], bfr, acc[ct], 0, 0, 0);
    }
  }
  __syncthreads();
  #pragma unroll
  for (int ct = 0; ct < 2; ++ct){
    #pragma unroll
    for (int q = 0; q < 4; ++q)
      cbuf[(wid*16 + 4*g + q)*36 + ct*16 + r] = acc[ct][q];
  }
  __syncthreads();
  {
    int row = tid >> 2, q = tid & 3;
    int grow = base + row;
    if (grow < N_NODES){
      const float* cp = &cbuf[row*36 + q*8];
      float4 c0 = *(const float4*)(cp);
      float4 c1 = *(const float4*)(cp + 4);
      *(uint4*)(h2b + (size_t)grow*16 + q*4) =
        make_uint4(pack_bf16(c0.x,c0.y), pack_bf16(c0.z,c0.w),
                   pack_bf16(c1.x,c1.y), pack_bf16(c1.z,c1.w));
    }
  }
  if (tid < 64){
    int grow = base + tid;
    if (grow < N_NODES){
      const float* cp = &cbuf[tid*36];
      float ps = 0.f, pd = 0.f;
      #pragma unroll
      for (int i = 0; i < 8; ++i){
        float4 c4 = *(const float4*)(cp + 4*i);
        ps += c4.x*attS[4*i] + c4.y*attS[4*i+1] + c4.z*attS[4*i+2] + c4.w*attS[4*i+3];
        pd += c4.x*attD[4*i] + c4.y*attD[4*i+1] + c4.z*attD[4*i+2] + c4.w*attD[4*i+3];
      }
      asrc[grow] = ps; adst[grow] = pd;
    }
  }
}

// ---------------- conv2: wave/node; bf16 rows, no max-subtraction ----------------------
__global__ __launch_bounds__(256) void k_conv2(const unsigned* __restrict__ off,
    const int* __restrict__ csr_src, const unsigned* __restrict__ h2b,
    const float* __restrict__ asrc, const float* __restrict__ adst,
    const float* __restrict__ b2, float* __restrict__ hout)
{
  __shared__ uint2 st[4][66];     // {exp_bits, row_byte_off}
  int w    = threadIdx.x >> 6;
  int lane = threadIdx.x & 63;
  int n = blockIdx.x*4 + w;
  if (n >= N_NODES) return;
  unsigned s0 = off[n];
  int deg = (int)(off[n+1] - s0);
  float ad = adst[n];
  int cl = lane & 7;              // feature slot: floats 4*cl..4*cl+3
  const char* hbase = (const char*)h2b + 8*cl;
  float4 acc = make_float4(0,0,0,0);
  float den = 0.f;

  if (deg <= 64){
    unsigned boff = 0;
    float e = 0.f;
    if (lane < deg){
      int idx = csr_src[s0 + lane];
      boff = ((unsigned)idx) << 6;          // 64 B bf16 row
      e = __expf(leaky02(asrc[idx] + ad));
    }
    st[w][lane] = make_uint2(__float_as_uint(e), boff);
    __builtin_amdgcn_wave_barrier();
    int g8 = lane >> 3;
    const uint2* sp = &st[w][g8];
    #pragma unroll 4
    for (int i = 0; i < deg; i += 8){
      uint2 p = sp[i];
      float es = __uint_as_float(p.x);
      uint2 hb = *(const uint2*)(hbase + p.y);
      acc.x += es*bf_lo(hb.x); acc.y += es*bf_hi(hb.x);
      acc.z += es*bf_lo(hb.y); acc.w += es*bf_hi(hb.y);
      den += es;
    }
    #pragma unroll
    for (int mm = 8; mm <= 32; mm <<= 1){
      acc.x += __shfl_xor(acc.x, mm); acc.y += __shfl_xor(acc.y, mm);
      acc.z += __shfl_xor(acc.z, mm); acc.w += __shfl_xor(acc.w, mm);
      den   += __shfl_xor(den, mm);
    }
  } else {
    for (int i = 0; i < deg; ++i){
      int s = csr_src[s0 + i];
      float ev = __expf(leaky02(asrc[s] + ad));
      uint2 hb = *(const uint2*)(hbase + (((unsigned)s) << 6));
      acc.x += ev*bf_lo(hb.x); acc.y += ev*bf_hi(hb.x);
      acc.z += ev*bf_lo(hb.y); acc.w += ev*bf_hi(hb.y);
      den += ev;
    }
  }
  if (lane < 8){
    float inv = 1.f/(den + 1e-16f);
    float4 bv = ((const float4*)b2)[cl];
    float4 o;
    o.x = acc.x*inv + bv.x; o.y = acc.y*inv + bv.y;
    o.z = acc.z*inv + bv.z; o.w = acc.w*inv + bv.w;
    *(float4*)(hout + (size_t)n*32 + 4*cl) = o;
  }
}

// ---------------- pool + fused final MLP (last-block pattern) --------------------------
__global__ __launch_bounds__(256) void k_poolf(const int* __restrict__ batch,
    const float* __restrict__ hout, float* __restrict__ gmean, unsigned* __restrict__ ctr,
    const float* __restrict__ l1w, const float* __restrict__ l1b,
    const float* __restrict__ l2w, const float* __restrict__ l2b, float* __restrict__ out)
{
  int g = blockIdx.x;
  int a = 0, b = N_NODES;
  while (a < b){ int mid = (a+b)>>1; if (batch[mid] < g) a = mid+1; else b = mid; }
  int lo = a;
  b = N_NODES;
  while (a < b){ int mid = (a+b)>>1; if (batch[mid] < g+1) a = mid+1; else b = mid; }
  int hi = a;
  int c = threadIdx.x & 31, rg = threadIdx.x >> 5;
  float s = 0.f;
  for (int r = lo + rg; r < hi; r += 8) s += hout[(size_t)r*32 + c];
  __shared__ float red[8][32];
  red[rg][c] = s;
  __syncthreads();
  if (rg == 0){
    float t = 0.f;
    #pragma unroll
    for (int k = 0; k < 8; ++k) t += red[k][c];
    gmean[g*32 + c] = t / fmaxf((float)(hi - lo), 1.0f);
  }
  // last finishing block runs the tiny final MLP
  __syncthreads();
  __threadfence();
  __shared__ unsigned rank;
  if (threadIdx.x == 0) rank = atomicAdd(ctr, 1u);
  __syncthreads();
  if (rank == NG - 1){
    __threadfence();
    int t = threadIdx.x;
    if (t < NG){
      float gv[32];
      #pragma unroll
      for (int j = 0; j < 32; ++j) gv[j] = gmean[t*32 + j];
      float o = l2b[0];
      #pragma unroll
      for (int k = 0; k < 16; ++k){
        float hv = l1b[k];
        #pragma unroll
        for (int j = 0; j < 32; ++j) hv += gv[j]*l1w[j*16 + k];
        o += eluf(hv) * l2w[k];
      }
      out[t] = o;
    }
  }
}

extern "C" void kernel_launch(void* const* d_in, const int* in_sizes, int n_in,
                              void* d_out, int out_size, void* d_ws, size_t ws_size,
                              hipStream_t stream) {
  const float* x     = (const float*)d_in[0];
  const int*   ei    = (const int*)  d_in[1];
  const int*   batch = (const int*)  d_in[2];
  const float* W1    = (const float*)d_in[3];
  const float* attS1 = (const float*)d_in[4];
  const float* attD1 = (const float*)d_in[5];
  const float* b1    = (const float*)d_in[6];
  const float* W2    = (const float*)d_in[7];
  const float* attS2 = (const float*)d_in[8];
  const float* attD2 = (const float*)d_in[9];
  const float* b2    = (const float*)d_in[10];
  const float* l1w   = (const float*)d_in[11];
  const float* l1b   = (const float*)d_in[12];
  const float* l2w   = (const float*)d_in[13];
  const float* l2b   = (const float*)d_in[14];
  float* out = (float*)d_out;

  char* w = (char*)d_ws;
  auto alloc = [&](size_t elems) -> void* {
    void* p = (void*)w;
    w += ((elems*4 + 255)/256)*256;
    return p;
  };
  unsigned* csr_off = (unsigned*)alloc(N_NODES + 1);
  unsigned* cnt     = (unsigned*)alloc(SCANN);
  unsigned* basev   = (unsigned*)alloc(SCANN);
  unsigned* staging = (unsigned*)alloc(ETOT);
  int*      csr_src = (int*)     alloc(ETOT);
  unsigned* wt1g  = (unsigned*)alloc(128*64);               // bf16 W1^T [128c][128k]
  unsigned* wt2g  = (unsigned*)alloc(32*64);                // bf16 W2^T [32c][128k]
  unsigned* h1f   = (unsigned*)alloc((size_t)N_NODES*32);   // fp8-packed [N,128]
  float*    asrc1 = (float*)alloc((size_t)N_NODES*4);
  float*    adst1 = (float*)alloc((size_t)N_NODES*4);
  unsigned* helu_b= (unsigned*)alloc((size_t)N_NODES*64);   // bf16-packed [N,128]
  unsigned* h2b   = (unsigned*)alloc((size_t)N_NODES*16);   // bf16-packed [N,32]
  float*    asrc2 = (float*)alloc(N_NODES);
  float*    adst2 = (float*)alloc(N_NODES);
  float*    hout  = (float*)alloc((size_t)N_NODES*32);
  float*    gmean = (float*)alloc(NG*32);
  unsigned* ctr   = (unsigned*)alloc(1);

  hipMemsetAsync(ctr, 0, 4, stream);

  k_hist  <<<NCHUNK + 160, 256, 0, stream>>>(ei, cnt, W1, W2, wt1g, wt2g);
  g_scanM <<<GSB, 256, 0, stream>>>(cnt, basev, SCANN);
  k_pg    <<<NCHUNK + GB1, 256, 0, stream>>>(ei, basev, staging,
                                             x, wt1g, attS1, attD1, h1f, asrc1, adst1);
  k_csr   <<<NBUCK, 256, 0, stream>>>(basev, staging, csr_off, csr_src);

  k_conv1<<<(N_NODES + 3)/4, 256, 0, stream>>>(csr_off, csr_src, h1f, asrc1, adst1, b1, helu_b);
  k_gemm2<<<(N_NODES + 63)/64, 256, 0, stream>>>(helu_b, wt2g, attS2, attD2, h2b, asrc2, adst2);
  k_conv2<<<(N_NODES + 3)/4, 256, 0, stream>>>(csr_off, csr_src, h2b, asrc2, adst2, b2, hout);
  k_poolf<<<NG, 256, 0, stream>>>(batch, hout, gmean, ctr, l1w, l1b, l2w, l2b, out);
}

// Round 17
// 162.977 us; speedup vs baseline: 1.1113x; 1.1113x over previous
//
#include <hip/hip_runtime.h>
#include <math.h>

#define N_NODES 50000
#define N_EDGES 800000
#define ETOT (N_EDGES + N_NODES)
#define NG 64
#define NBUCK 196                 // dst buckets of 256 nodes
#define CHUNK 4096
#define NCHUNK ((ETOT + CHUNK - 1)/CHUNK)   // 208
#define SCANN (NBUCK*NCHUNK)      // 40768
#define GSB ((SCANN + 255)/256)   // 160
#define GB1 ((N_NODES + 63)/64)   // 782 gemm1 blocks

typedef float vf2 __attribute__((ext_vector_type(2)));
typedef short bf16x8 __attribute__((ext_vector_type(8)));
typedef float f32x4 __attribute__((ext_vector_type(4)));

__device__ __forceinline__ float leaky02(float a){ return a > 0.f ? a : 0.2f*a; }
__device__ __forceinline__ float eluf(float v){ return v > 0.f ? v : expm1f(v); }

// round-to-nearest-even f32->bf16, packed pair (a low, b high)
__device__ __forceinline__ unsigned pack_bf16(float a, float b){
  unsigned ua = __float_as_uint(a); ua += 0x7fffu + ((ua >> 16) & 1u);
  unsigned ub = __float_as_uint(b); ub += 0x7fffu + ((ub >> 16) & 1u);
  return (ua >> 16) | (ub & 0xffff0000u);
}
__device__ __forceinline__ float bf_lo(unsigned v){ return __uint_as_float(v << 16); }
__device__ __forceinline__ float bf_hi(unsigned v){ return __uint_as_float(v & 0xffff0000u); }

// fp8 e4m3 pack via HW cvt (self-consistent internal format)
__device__ __forceinline__ unsigned pack_fp8x4(float4 a){
  int v = __builtin_amdgcn_cvt_pk_fp8_f32(a.x, a.y, 0, false);
  v = __builtin_amdgcn_cvt_pk_fp8_f32(a.z, a.w, v, true);
  return (unsigned)v;
}

// ---------------- hist (+ fused weight prep in extra blocks) ---------------------------
__global__ __launch_bounds__(256) void k_hist(const int* __restrict__ ei,
    unsigned* __restrict__ cnt, const float* __restrict__ W1, const float* __restrict__ W2,
    unsigned* __restrict__ wt1, unsigned* __restrict__ wt2){
  if (blockIdx.x >= NCHUNK){
    int b = blockIdx.x - NCHUNK;   // 0..159
    int t = threadIdx.x;
    if (t < 64){
      if (b < 128){
        float a = W1[(size_t)(2*t)*128 + b];
        float c = W1[(size_t)(2*t+1)*128 + b];
        wt1[b*64 + t] = pack_bf16(a, c);
      } else {
        int cc = b - 128;
        float a = W2[(size_t)(2*t)*32 + cc];
        float c = W2[(size_t)(2*t+1)*32 + cc];
        wt2[cc*64 + t] = pack_bf16(a, c);
      }
    }
    return;
  }
  __shared__ unsigned hist[NBUCK];
  int tid = threadIdx.x;
  for (int t = tid; t < NBUCK; t += 256) hist[t] = 0;
  __syncthreads();
  int base = blockIdx.x * CHUNK;
  #pragma unroll
  for (int i = 0; i < CHUNK/256; ++i){
    int e = base + i*256 + tid;
    if (e < ETOT){
      int d = (e < N_EDGES) ? ei[N_EDGES + e] : (e - N_EDGES);
      atomicAdd(&hist[d >> 8], 1u);
    }
  }
  __syncthreads();
  for (int t = tid; t < NBUCK; t += 256) cnt[t*NCHUNK + blockIdx.x] = hist[t];
}

// ---------------- merged exclusive scan: base-sum of predecessors + local scan ---------
__global__ __launch_bounds__(256) void g_scanM(const unsigned* __restrict__ in,
    unsigned* __restrict__ out, int n){
  __shared__ unsigned red[4];
  __shared__ unsigned ts[256];
  int t = threadIdx.x, blk = blockIdx.x, i = blk*256 + t;
  unsigned s = 0;
  for (int j = t; j < blk*256; j += 256) s += in[j];
  #pragma unroll
  for (int o = 32; o >= 1; o >>= 1) s += __shfl_xor(s, o);
  if ((t & 63) == 0) red[t >> 6] = s;
  unsigned v = (i < n) ? in[i] : 0u;
  ts[t] = v;
  __syncthreads();
  unsigned base = red[0] + red[1] + red[2] + red[3];
  for (int o = 1; o < 256; o <<= 1){
    unsigned u = (t >= o) ? ts[t-o] : 0u;
    __syncthreads();
    ts[t] += u;
    __syncthreads();
  }
  if (i < n) out[i] = base + ts[t] - v;
}

// ---------------- fused: edge partition (208 blocks) || GEMM1 (782 blocks) -------------
__global__ __launch_bounds__(256) void k_pg(const int* __restrict__ ei,
    const unsigned* __restrict__ basev, unsigned* __restrict__ staging,
    const float* __restrict__ x, const unsigned* __restrict__ wt1,
    const float* __restrict__ attS, const float* __restrict__ attD,
    unsigned* __restrict__ h1f, float* __restrict__ asrc, float* __restrict__ adst)
{
  __shared__ unsigned cur[NBUCK];
  __shared__ __align__(16) short xs[64*136];    // 17.4 KB bf16
  __shared__ __align__(16) short wb[128*136];   // 34.8 KB bf16; reused as Cst f32 [64][132]
  int tid = threadIdx.x;

  if (blockIdx.x < NCHUNK){
    // ---- edge partition ----
    for (int t = tid; t < NBUCK; t += 256) cur[t] = basev[t*NCHUNK + blockIdx.x];
    __syncthreads();
    int base = blockIdx.x * CHUNK;
    #pragma unroll
    for (int i = 0; i < CHUNK/256; ++i){
      int e = base + i*256 + tid;
      if (e < ETOT){
        int s, d;
        if (e < N_EDGES){ s = ei[e]; d = ei[N_EDGES + e]; } else { s = d = e - N_EDGES; }
        unsigned pos = atomicAdd(&cur[d >> 8], 1u);
        staging[pos] = (unsigned)s | ((unsigned)(d & 255) << 16);
      }
    }
    return;
  }

  // ---- GEMM1 (MFMA bf16): h1 = x @ W1 -> fp8; alphas from f32 acc ----
  float* Cst = (float*)wb;
  int base = (blockIdx.x - NCHUNK) * 64;
  {
    int row = tid >> 2, q = tid & 3;
    const float* src = x + (size_t)(base + row)*128 + q*32;
    bool valid = (base + row) < N_NODES;
    #pragma unroll
    for (int i = 0; i < 8; ++i){
      float4 v = valid ? *(const float4*)(src + 4*i) : make_float4(0,0,0,0);
      *(uint2*)(&xs[row*136 + q*32 + 4*i]) = make_uint2(pack_bf16(v.x, v.y), pack_bf16(v.z, v.w));
    }
  }
  {
    int c = tid >> 1, h = tid & 1;
    #pragma unroll
    for (int i = 0; i < 8; ++i){
      uint4 v = *(const uint4*)(wt1 + c*64 + h*32 + 4*i);
      *(uint4*)(&wb[c*136 + h*64 + 8*i]) = v;
    }
  }
  __syncthreads();
  int lane = tid & 63, wid = tid >> 6;
  int r = lane & 15, g = lane >> 4;
  bf16x8 afr[4];
  #pragma unroll
  for (int kk = 0; kk < 4; ++kk)
    afr[kk] = *(const bf16x8*)(&xs[(wid*16 + r)*136 + kk*32 + g*8]);
  f32x4 acc[8];
  #pragma unroll
  for (int ct = 0; ct < 8; ++ct){ acc[ct][0]=0.f; acc[ct][1]=0.f; acc[ct][2]=0.f; acc[ct][3]=0.f; }
  #pragma unroll
  for (int ct = 0; ct < 8; ++ct){
    #pragma unroll
    for (int kk = 0; kk < 4; ++kk){
      bf16x8 bfr = *(const bf16x8*)(&wb[(ct*16 + r)*136 + kk*32 + g*8]);
      acc[ct] = __builtin_amdgcn_mfma_f32_16x16x32_bf16(afr[kk], bfr, acc[ct], 0, 0, 0);
    }
  }
  __syncthreads();   // everyone done reading wb; reuse as Cst
  #pragma unroll
  for (int ct = 0; ct < 8; ++ct){
    #pragma unroll
    for (int q = 0; q < 4; ++q)
      Cst[(wid*16 + 4*g + q)*132 + ct*16 + r] = acc[ct][q];
  }
  __syncthreads();
  {
    int row = tid >> 2, hd = tid & 3;
    int grow = base + row;
    if (grow < N_NODES){
      const float* cp = &Cst[row*132 + hd*32];
      const float* aS = attS + hd*32;
      const float* aD = attD + hd*32;
      float ps = 0.f, pd = 0.f;
      unsigned u[8];
      #pragma unroll
      for (int i = 0; i < 8; ++i){
        float4 c4 = *(const float4*)(cp + 4*i);
        ps += c4.x*aS[4*i] + c4.y*aS[4*i+1] + c4.z*aS[4*i+2] + c4.w*aS[4*i+3];
        pd += c4.x*aD[4*i] + c4.y*aD[4*i+1] + c4.z*aD[4*i+2] + c4.w*aD[4*i+3];
        u[i] = pack_fp8x4(c4);
      }
      unsigned* dst = h1f + (size_t)grow*32 + hd*8;
      *(uint4*)(dst)     = make_uint4(u[0], u[1], u[2], u[3]);
      *(uint4*)(dst + 4) = make_uint4(u[4], u[5], u[6], u[7]);
      asrc[grow*4 + hd] = ps;
      adst[grow*4 + hd] = pd;
    }
  }
}

__global__ __launch_bounds__(256) void k_csr(const unsigned* __restrict__ basev,
    const unsigned* __restrict__ staging, unsigned* __restrict__ off,
    int* __restrict__ csr_src){
  __shared__ unsigned ts[256], cur[256];
  int tid = threadIdx.x, b = blockIdx.x;
  unsigned start = basev[b*NCHUNK];
  unsigned end = (b == NBUCK-1) ? (unsigned)ETOT : basev[(b+1)*NCHUNK];
  ts[tid] = 0;
  __syncthreads();
  for (unsigned i = start + tid; i < end; i += 256)
    atomicAdd(&ts[staging[i] >> 16], 1u);
  __syncthreads();
  unsigned v = ts[tid];
  for (int o = 1; o < 256; o <<= 1){
    unsigned u = (tid >= o) ? ts[tid-o] : 0u;
    __syncthreads();
    ts[tid] += u;
    __syncthreads();
  }
  unsigned excl = ts[tid] - v;
  int node = (b << 8) + tid;
  if (node < N_NODES) off[node] = start + excl;
  if (b == 0 && tid == 0) off[N_NODES] = (unsigned)ETOT;
  cur[tid] = excl;
  __syncthreads();
  for (unsigned i = start + tid; i < end; i += 256){
    unsigned p = staging[i];
    unsigned pos = atomicAdd(&cur[p >> 16], 1u);
    csr_src[start + pos] = (int)(p & 0xffffu);
  }
}

// ---------------- conv1: wave/node; fp8 rows, no max-subtraction -----------------------
__global__ __launch_bounds__(256) void k_conv1(const unsigned* __restrict__ off,
    const int* __restrict__ csr_src, const unsigned* __restrict__ h1f,
    const float* __restrict__ asrc, const float* __restrict__ adst,
    const float* __restrict__ b1, unsigned* __restrict__ helu_b)
{
  __shared__ uint2 st[4][4][66];  // [wave][head][edge] = {exp_bits, row_byte_off}
  int w    = threadIdx.x >> 6;
  int lane = threadIdx.x & 63;
  int n = blockIdx.x*4 + w;
  if (n >= N_NODES) return;
  unsigned s0 = off[n];
  int deg = (int)(off[n+1] - s0);
  float4 ad = *(const float4*)(adst + (size_t)n*4);
  int cl = lane & 31;             // feature slot: features 4*cl..4*cl+3
  int h  = cl >> 3;               // head of this slot
  const char* hbase = (const char*)h1f + 4*cl;
  float4 acc = make_float4(0,0,0,0);
  float den = 0.f;

  if (deg <= 64){
    unsigned boff = 0;
    float e0=0.f, e1=0.f, e2=0.f, e3=0.f;
    if (lane < deg){
      int idx = csr_src[s0 + lane];
      boff = ((unsigned)idx) << 7;          // 128 B fp8 row
      float4 as = *(const float4*)(asrc + (size_t)idx*4);
      e0 = __expf(leaky02(as.x + ad.x));
      e1 = __expf(leaky02(as.y + ad.y));
      e2 = __expf(leaky02(as.z + ad.z));
      e3 = __expf(leaky02(as.w + ad.w));
    }
    st[w][0][lane] = make_uint2(__float_as_uint(e0), boff);
    st[w][1][lane] = make_uint2(__float_as_uint(e1), boff);
    st[w][2][lane] = make_uint2(__float_as_uint(e2), boff);
    st[w][3][lane] = make_uint2(__float_as_uint(e3), boff);
    __builtin_amdgcn_wave_barrier();        // wave-coherent LDS, no s_barrier
    int half = lane >> 5;
    const uint2* sp = &st[w][h][half];
    #pragma unroll 8
    for (int i = 0; i < deg; i += 2){
      uint2 p = sp[i];
      float es = __uint_as_float(p.x);
      unsigned hb = *(const unsigned*)(hbase + p.y);
      vf2 p0 = __builtin_amdgcn_cvt_pk_f32_fp8((int)hb, false);
      vf2 p1 = __builtin_amdgcn_cvt_pk_f32_fp8((int)hb, true);
      acc.x += es*p0[0]; acc.y += es*p0[1];
      acc.z += es*p1[0]; acc.w += es*p1[1];
      den += es;
    }
    acc.x += __shfl_xor(acc.x, 32); acc.y += __shfl_xor(acc.y, 32);
    acc.z += __shfl_xor(acc.z, 32); acc.w += __shfl_xor(acc.w, 32);
    den   += __shfl_xor(den, 32);
  } else {
    float adh = (h==0) ? ad.x : (h==1) ? ad.y : (h==2) ? ad.z : ad.w;
    for (int i = 0; i < deg; ++i){
      int s = csr_src[s0 + i];
      float ev = __expf(leaky02(asrc[s*4 + h] + adh));
      unsigned hb = *(const unsigned*)(hbase + (((unsigned)s) << 7));
      vf2 p0 = __builtin_amdgcn_cvt_pk_f32_fp8((int)hb, false);
      vf2 p1 = __builtin_amdgcn_cvt_pk_f32_fp8((int)hb, true);
      acc.x += ev*p0[0]; acc.y += ev*p0[1];
      acc.z += ev*p1[0]; acc.w += ev*p1[1];
      den += ev;
    }
  }
  if (lane < 32){
    float inv = 1.f/(den + 1e-16f);
    float4 bv = ((const float4*)b1)[cl];
    float ox = eluf(acc.x*inv + bv.x), oy = eluf(acc.y*inv + bv.y);
    float oz = eluf(acc.z*inv + bv.z), ow = eluf(acc.w*inv + bv.w);
    *(uint2*)(helu_b + (size_t)n*64 + 2*cl) = make_uint2(pack_bf16(ox, oy), pack_bf16(oz, ow));
  }
}

// ---------------- GEMM2 (MFMA bf16): h2 = helu @ W2, h2 -> bf16; scalar alphas ---------
__global__ __launch_bounds__(256) void k_gemm2(const unsigned* __restrict__ helu_b,
    const unsigned* __restrict__ wt2, const float* __restrict__ attS,
    const float* __restrict__ attD, unsigned* __restrict__ h2b,
    float* __restrict__ asrc, float* __restrict__ adst)
{
  __shared__ __align__(16) short xs[64*136];    // 17.4 KB
  __shared__ __align__(16) float cbuf[64*36];   // 9.2 KB f32; first 8.7 KB doubles as Wt2
  short* w2 = (short*)cbuf;
  int tid = threadIdx.x;
  int base = blockIdx.x * 64;
  {
    int row = tid >> 2, q = tid & 3;
    bool valid = (base + row) < N_NODES;
    const unsigned* src = helu_b + (size_t)(base + row)*64 + q*16;
    #pragma unroll
    for (int i = 0; i < 4; ++i){
      uint4 v = valid ? *(const uint4*)(src + 4*i) : make_uint4(0,0,0,0);
      *(uint4*)(&xs[row*136 + q*32 + 8*i]) = v;
    }
  }
  {
    int c = tid >> 3, h = tid & 7;
    uint4 v0 = *(const uint4*)(wt2 + c*64 + h*8);
    uint4 v1 = *(const uint4*)(wt2 + c*64 + h*8 + 4);
    *(uint4*)(&w2[c*136 + h*16])     = v0;
    *(uint4*)(&w2[c*136 + h*16 + 8]) = v1;
  }
  __syncthreads();
  int lane = tid & 63, wid = tid >> 6;
  int r = lane & 15, g = lane >> 4;
  bf16x8 afr[4];
  #pragma unroll
  for (int kk = 0; kk < 4; ++kk)
    afr[kk] = *(const bf16x8*)(&xs[(wid*16 + r)*136 + kk*32 + g*8]);
  f32x4 acc[2];
  #pragma unroll
  for (int ct = 0; ct < 2; ++ct){ acc[ct][0]=0.f; acc[ct][1]=0.f; acc[ct][2]=0.f; acc[ct][3]=0.f; }
  #pragma unroll
  for (int ct = 0; ct < 2; ++ct){
    #pragma unroll
    for (int kk = 0; kk < 4; ++kk){
      bf16x8 bfr = *(const bf16x8*)(&w2[(ct*16 + r)*136 + kk*32 + g*8]);
      acc[ct] = __builtin_amdgcn_mfma_f32_16x16x32_bf16(afr[kk], bfr, acc[ct], 0, 0, 0);
    }
  }
  __syncthreads();
  #pragma unroll
  for (int ct = 0; ct < 2; ++ct){
    #pragma unroll
    for (int q = 0; q < 4; ++q)
      cbuf[(wid*16 + 4*g + q)*36 + ct*16 + r] = acc[ct][q];
  }
  __syncthreads();
  {
    int row = tid >> 2, q = tid & 3;
    int grow = base + row;
    if (grow < N_NODES){
      const float* cp = &cbuf[row*36 + q*8];
      float4 c0 = *(const float4*)(cp);
      float4 c1 = *(const float4*)(cp + 4);
      *(uint4*)(h2b + (size_t)grow*16 + q*4) =
        make_uint4(pack_bf16(c0.x,c0.y), pack_bf16(c0.z,c0.w),
                   pack_bf16(c1.x,c1.y), pack_bf16(c1.z,c1.w));
    }
  }
  if (tid < 64){
    int grow = base + tid;
    if (grow < N_NODES){
      const float* cp = &cbuf[tid*36];
      float ps = 0.f, pd = 0.f;
      #pragma unroll
      for (int i = 0; i < 8; ++i){
        float4 c4 = *(const float4*)(cp + 4*i);
        ps += c4.x*attS[4*i] + c4.y*attS[4*i+1] + c4.z*attS[4*i+2] + c4.w*attS[4*i+3];
        pd += c4.x*attD[4*i] + c4.y*attD[4*i+1] + c4.z*attD[4*i+2] + c4.w*attD[4*i+3];
      }
      asrc[grow] = ps; adst[grow] = pd;
    }
  }
}

// ---------------- conv2: wave/node; bf16 rows, no max-subtraction ----------------------
__global__ __launch_bounds__(256) void k_conv2(const unsigned* __restrict__ off,
    const int* __restrict__ csr_src, const unsigned* __restrict__ h2b,
    const float* __restrict__ asrc, const float* __restrict__ adst,
    const float* __restrict__ b2, float* __restrict__ hout)
{
  __shared__ uint2 st[4][66];     // {exp_bits, row_byte_off}
  int w    = threadIdx.x >> 6;
  int lane = threadIdx.x & 63;
  int n = blockIdx.x*4 + w;
  if (n >= N_NODES) return;
  unsigned s0 = off[n];
  int deg = (int)(off[n+1] - s0);
  float ad = adst[n];
  int cl = lane & 7;              // feature slot: floats 4*cl..4*cl+3
  const char* hbase = (const char*)h2b + 8*cl;
  float4 acc = make_float4(0,0,0,0);
  float den = 0.f;

  if (deg <= 64){
    unsigned boff = 0;
    float e = 0.f;
    if (lane < deg){
      int idx = csr_src[s0 + lane];
      boff = ((unsigned)idx) << 6;          // 64 B bf16 row
      e = __expf(leaky02(asrc[idx] + ad));
    }
    st[w][lane] = make_uint2(__float_as_uint(e), boff);
    __builtin_amdgcn_wave_barrier();
    int g8 = lane >> 3;
    const uint2* sp = &st[w][g8];
    #pragma unroll 4
    for (int i = 0; i < deg; i += 8){
      uint2 p = sp[i];
      float es = __uint_as_float(p.x);
      uint2 hb = *(const uint2*)(hbase + p.y);
      acc.x += es*bf_lo(hb.x); acc.y += es*bf_hi(hb.x);
      acc.z += es*bf_lo(hb.y); acc.w += es*bf_hi(hb.y);
      den += es;
    }
    #pragma unroll
    for (int mm = 8; mm <= 32; mm <<= 1){
      acc.x += __shfl_xor(acc.x, mm); acc.y += __shfl_xor(acc.y, mm);
      acc.z += __shfl_xor(acc.z, mm); acc.w += __shfl_xor(acc.w, mm);
      den   += __shfl_xor(den, mm);
    }
  } else {
    for (int i = 0; i < deg; ++i){
      int s = csr_src[s0 + i];
      float ev = __expf(leaky02(asrc[s] + ad));
      uint2 hb = *(const uint2*)(hbase + (((unsigned)s) << 6));
      acc.x += ev*bf_lo(hb.x); acc.y += ev*bf_hi(hb.x);
      acc.z += ev*bf_lo(hb.y); acc.w += ev*bf_hi(hb.y);
      den += ev;
    }
  }
  if (lane < 8){
    float inv = 1.f/(den + 1e-16f);
    float4 bv = ((const float4*)b2)[cl];
    float4 o;
    o.x = acc.x*inv + bv.x; o.y = acc.y*inv + bv.y;
    o.z = acc.z*inv + bv.z; o.w = acc.w*inv + bv.w;
    *(float4*)(hout + (size_t)n*32 + 4*cl) = o;
  }
}

// ---------------- pool: 8 blocks per graph -> deterministic partials -------------------
__global__ __launch_bounds__(256) void k_pool(const int* __restrict__ batch,
    const float* __restrict__ hout, float* __restrict__ gpart)
{
  int g = blockIdx.x >> 3, sub = blockIdx.x & 7;
  int a = 0, b = N_NODES;
  while (a < b){ int mid = (a+b)>>1; if (batch[mid] < g) a = mid+1; else b = mid; }
  int lo = a;
  b = N_NODES;
  while (a < b){ int mid = (a+b)>>1; if (batch[mid] < g+1) a = mid+1; else b = mid; }
  int hi = a;
  int c = threadIdx.x & 31, rg = threadIdx.x >> 5;   // 8 row groups
  float s = 0.f;
  for (int r = lo + sub*8 + rg; r < hi; r += 64) s += hout[(size_t)r*32 + c];
  __shared__ float red[8][32];
  red[rg][c] = s;
  __syncthreads();
  if (rg == 0){
    float t = 0.f;
    #pragma unroll
    for (int k = 0; k < 8; ++k) t += red[k][c];
    gpart[(size_t)blockIdx.x*32 + c] = t;
  }
}

// ---------------- final: sum partials, mean, MLP (64 graphs, 1 block) ------------------
__global__ void k_final(const int* __restrict__ batch, const float* __restrict__ gpart,
    const float* __restrict__ l1w, const float* __restrict__ l1b,
    const float* __restrict__ l2w, const float* __restrict__ l2b, float* __restrict__ out)
{
  int t = threadIdx.x;
  if (t >= NG) return;
  int a = 0, b = N_NODES;
  while (a < b){ int mid = (a+b)>>1; if (batch[mid] < t) a = mid+1; else b = mid; }
  int lo = a;
  b = N_NODES;
  while (a < b){ int mid = (a+b)>>1; if (batch[mid] < t+1) a = mid+1; else b = mid; }
  int hi = a;
  float cinv = 1.f / fmaxf((float)(hi - lo), 1.0f);
  float g[32];
  #pragma unroll
  for (int j = 0; j < 32; ++j){
    float s = 0.f;
    #pragma unroll
    for (int p = 0; p < 8; ++p) s += gpart[(size_t)(t*8 + p)*32 + j];
    g[j] = s * cinv;
  }
  float o = l2b[0];
  #pragma unroll
  for (int k = 0; k < 16; ++k){
    float hv = l1b[k];
    #pragma unroll
    for (int j = 0; j < 32; ++j) hv += g[j]*l1w[j*16 + k];
    o += eluf(hv) * l2w[k];
  }
  out[t] = o;
}

extern "C" void kernel_launch(void* const* d_in, const int* in_sizes, int n_in,
                              void* d_out, int out_size, void* d_ws, size_t ws_size,
                              hipStream_t stream) {
  const float* x     = (const float*)d_in[0];
  const int*   ei    = (const int*)  d_in[1];
  const int*   batch = (const int*)  d_in[2];
  const float* W1    = (const float*)d_in[3];
  const float* attS1 = (const float*)d_in[4];
  const float* attD1 = (const float*)d_in[5];
  const float* b1    = (const float*)d_in[6];
  const float* W2    = (const float*)d_in[7];
  const float* attS2 = (const float*)d_in[8];
  const float* attD2 = (const float*)d_in[9];
  const float* b2    = (const float*)d_in[10];
  const float* l1w   = (const float*)d_in[11];
  const float* l1b   = (const float*)d_in[12];
  const float* l2w   = (const float*)d_in[13];
  const float* l2b   = (const float*)d_in[14];
  float* out = (float*)d_out;

  char* w = (char*)d_ws;
  auto alloc = [&](size_t elems) -> void* {
    void* p = (void*)w;
    w += ((elems*4 + 255)/256)*256;
    return p;
  };
  unsigned* csr_off = (unsigned*)alloc(N_NODES + 1);
  unsigned* cnt     = (unsigned*)alloc(SCANN);
  unsigned* basev   = (unsigned*)alloc(SCANN);
  unsigned* staging = (unsigned*)alloc(ETOT);
  int*      csr_src = (int*)     alloc(ETOT);
  unsigned* wt1g  = (unsigned*)alloc(128*64);               // bf16 W1^T [128c][128k]
  unsigned* wt2g  = (unsigned*)alloc(32*64);                // bf16 W2^T [32c][128k]
  unsigned* h1f   = (unsigned*)alloc((size_t)N_NODES*32);   // fp8-packed [N,128]
  float*    asrc1 = (float*)alloc((size_t)N_NODES*4);
  float*    adst1 = (float*)alloc((size_t)N_NODES*4);
  unsigned* helu_b= (unsigned*)alloc((size_t)N_NODES*64);   // bf16-packed [N,128]
  unsigned* h2b   = (unsigned*)alloc((size_t)N_NODES*16);   // bf16-packed [N,32]
  float*    asrc2 = (float*)alloc(N_NODES);
  float*    adst2 = (float*)alloc(N_NODES);
  float*    hout  = (float*)alloc((size_t)N_NODES*32);
  float*    gpart = (float*)alloc(NG*8*32);

  k_hist  <<<NCHUNK + 160, 256, 0, stream>>>(ei, cnt, W1, W2, wt1g, wt2g);
  g_scanM <<<GSB, 256, 0, stream>>>(cnt, basev, SCANN);
  k_pg    <<<NCHUNK + GB1, 256, 0, stream>>>(ei, basev, staging,
                                             x, wt1g, attS1, attD1, h1f, asrc1, adst1);
  k_csr   <<<NBUCK, 256, 0, stream>>>(basev, staging, csr_off, csr_src);

  k_conv1<<<(N_NODES + 3)/4, 256, 0, stream>>>(csr_off, csr_src, h1f, asrc1, adst1, b1, helu_b);
  k_gemm2<<<(N_NODES + 63)/64, 256, 0, stream>>>(helu_b, wt2g, attS2, attD2, h2b, asrc2, adst2);
  k_conv2<<<(N_NODES + 3)/4, 256, 0, stream>>>(csr_off, csr_src, h2b, asrc2, adst2, b2, hout);
  k_pool <<<NG*8, 256, 0, stream>>>(batch, hout, gpart);
  k_final<<<1, 64, 0, stream>>>(batch, gpart, l1w, l1b, l2w, l2b, out);
}

// Round 18
// 154.434 us; speedup vs baseline: 1.1728x; 1.0553x over previous
//
#include <hip/hip_runtime.h>
#include <math.h>

#define N_NODES 50000
#define N_EDGES 800000
#define ETOT (N_EDGES + N_NODES)
#define NG 64
#define NBUCK 196                 // dst buckets of 256 nodes
#define CHUNK 4096
#define NCHUNK ((ETOT + CHUNK - 1)/CHUNK)   // 208
#define SCANN (NBUCK*NCHUNK)      // 40768
#define GSB ((SCANN + 255)/256)   // 160
#define GB1 ((N_NODES + 63)/64)   // 782 gemm1 blocks

typedef float vf2 __attribute__((ext_vector_type(2)));
typedef short bf16x8 __attribute__((ext_vector_type(8)));
typedef float f32x4 __attribute__((ext_vector_type(4)));

__device__ __forceinline__ float leaky02(float a){ return a > 0.f ? a : 0.2f*a; }
__device__ __forceinline__ float eluf(float v){ return v > 0.f ? v : expm1f(v); }

// round-to-nearest-even f32->bf16, packed pair (a low, b high)
__device__ __forceinline__ unsigned pack_bf16(float a, float b){
  unsigned ua = __float_as_uint(a); ua += 0x7fffu + ((ua >> 16) & 1u);
  unsigned ub = __float_as_uint(b); ub += 0x7fffu + ((ub >> 16) & 1u);
  return (ua >> 16) | (ub & 0xffff0000u);
}
__device__ __forceinline__ float bf_lo(unsigned v){ return __uint_as_float(v << 16); }
__device__ __forceinline__ float bf_hi(unsigned v){ return __uint_as_float(v & 0xffff0000u); }

// fp8 e4m3 pack via HW cvt (self-consistent internal format)
__device__ __forceinline__ unsigned pack_fp8x4(float4 a){
  int v = __builtin_amdgcn_cvt_pk_fp8_f32(a.x, a.y, 0, false);
  v = __builtin_amdgcn_cvt_pk_fp8_f32(a.z, a.w, v, true);
  return (unsigned)v;
}

// ---------------- hist (+ fused weight prep in extra blocks) ---------------------------
__global__ __launch_bounds__(256) void k_hist(const int* __restrict__ ei,
    unsigned* __restrict__ cnt, const float* __restrict__ W1, const float* __restrict__ W2,
    unsigned* __restrict__ wt1, unsigned* __restrict__ wt2){
  if (blockIdx.x >= NCHUNK){
    int b = blockIdx.x - NCHUNK;   // 0..159
    int t = threadIdx.x;
    if (t < 64){
      if (b < 128){
        float a = W1[(size_t)(2*t)*128 + b];
        float c = W1[(size_t)(2*t+1)*128 + b];
        wt1[b*64 + t] = pack_bf16(a, c);
      } else {
        int cc = b - 128;
        float a = W2[(size_t)(2*t)*32 + cc];
        float c = W2[(size_t)(2*t+1)*32 + cc];
        wt2[cc*64 + t] = pack_bf16(a, c);
      }
    }
    return;
  }
  __shared__ unsigned hist[NBUCK];
  int tid = threadIdx.x;
  for (int t = tid; t < NBUCK; t += 256) hist[t] = 0;
  __syncthreads();
  int base = blockIdx.x * CHUNK;
  #pragma unroll
  for (int i = 0; i < CHUNK/256; ++i){
    int e = base + i*256 + tid;
    if (e < ETOT){
      int d = (e < N_EDGES) ? ei[N_EDGES + e] : (e - N_EDGES);
      atomicAdd(&hist[d >> 8], 1u);
    }
  }
  __syncthreads();
  for (int t = tid; t < NBUCK; t += 256) cnt[t*NCHUNK + blockIdx.x] = hist[t];
}

// ---------------- merged exclusive scan: base-sum of predecessors + local scan ---------
__global__ __launch_bounds__(256) void g_scanM(const unsigned* __restrict__ in,
    unsigned* __restrict__ out, int n){
  __shared__ unsigned red[4];
  __shared__ unsigned ts[256];
  int t = threadIdx.x, blk = blockIdx.x, i = blk*256 + t;
  unsigned s = 0;
  for (int j = t; j < blk*256; j += 256) s += in[j];
  #pragma unroll
  for (int o = 32; o >= 1; o >>= 1) s += __shfl_xor(s, o);
  if ((t & 63) == 0) red[t >> 6] = s;
  unsigned v = (i < n) ? in[i] : 0u;
  ts[t] = v;
  __syncthreads();
  unsigned base = red[0] + red[1] + red[2] + red[3];
  for (int o = 1; o < 256; o <<= 1){
    unsigned u = (t >= o) ? ts[t-o] : 0u;
    __syncthreads();
    ts[t] += u;
    __syncthreads();
  }
  if (i < n) out[i] = base + ts[t] - v;
}

// ---------------- fused: edge partition (208 blocks) || GEMM1 (782 blocks) -------------
__global__ __launch_bounds__(256) void k_pg(const int* __restrict__ ei,
    const unsigned* __restrict__ basev, unsigned* __restrict__ staging,
    const float* __restrict__ x, const unsigned* __restrict__ wt1,
    const float* __restrict__ attS, const float* __restrict__ attD,
    unsigned* __restrict__ h1f, float* __restrict__ asrc, float* __restrict__ adst)
{
  __shared__ unsigned cur[NBUCK];
  __shared__ __align__(16) short xs[64*136];    // 17.4 KB bf16
  __shared__ __align__(16) short wb[128*136];   // 34.8 KB bf16; reused as Cst f32 [64][132]
  int tid = threadIdx.x;

  if (blockIdx.x < NCHUNK){
    // ---- edge partition ----
    for (int t = tid; t < NBUCK; t += 256) cur[t] = basev[t*NCHUNK + blockIdx.x];
    __syncthreads();
    int base = blockIdx.x * CHUNK;
    #pragma unroll
    for (int i = 0; i < CHUNK/256; ++i){
      int e = base + i*256 + tid;
      if (e < ETOT){
        int s, d;
        if (e < N_EDGES){ s = ei[e]; d = ei[N_EDGES + e]; } else { s = d = e - N_EDGES; }
        unsigned pos = atomicAdd(&cur[d >> 8], 1u);
        staging[pos] = (unsigned)s | ((unsigned)(d & 255) << 16);
      }
    }
    return;
  }

  // ---- GEMM1 (MFMA bf16): h1 = x @ W1 -> fp8; alphas from f32 acc ----
  float* Cst = (float*)wb;
  int base = (blockIdx.x - NCHUNK) * 64;
  {
    int row = tid >> 2, q = tid & 3;
    const float* src = x + (size_t)(base + row)*128 + q*32;
    bool valid = (base + row) < N_NODES;
    #pragma unroll
    for (int i = 0; i < 8; ++i){
      float4 v = valid ? *(const float4*)(src + 4*i) : make_float4(0,0,0,0);
      *(uint2*)(&xs[row*136 + q*32 + 4*i]) = make_uint2(pack_bf16(v.x, v.y), pack_bf16(v.z, v.w));
    }
  }
  {
    int c = tid >> 1, h = tid & 1;
    #pragma unroll
    for (int i = 0; i < 8; ++i){
      uint4 v = *(const uint4*)(wt1 + c*64 + h*32 + 4*i);
      *(uint4*)(&wb[c*136 + h*64 + 8*i]) = v;
    }
  }
  __syncthreads();
  int lane = tid & 63, wid = tid >> 6;
  int r = lane & 15, g = lane >> 4;
  bf16x8 afr[4];
  #pragma unroll
  for (int kk = 0; kk < 4; ++kk)
    afr[kk] = *(const bf16x8*)(&xs[(wid*16 + r)*136 + kk*32 + g*8]);
  f32x4 acc[8];
  #pragma unroll
  for (int ct = 0; ct < 8; ++ct){ acc[ct][0]=0.f; acc[ct][1]=0.f; acc[ct][2]=0.f; acc[ct][3]=0.f; }
  #pragma unroll
  for (int ct = 0; ct < 8; ++ct){
    #pragma unroll
    for (int kk = 0; kk < 4; ++kk){
      bf16x8 bfr = *(const bf16x8*)(&wb[(ct*16 + r)*136 + kk*32 + g*8]);
      acc[ct] = __builtin_amdgcn_mfma_f32_16x16x32_bf16(afr[kk], bfr, acc[ct], 0, 0, 0);
    }
  }
  __syncthreads();   // everyone done reading wb; reuse as Cst
  #pragma unroll
  for (int ct = 0; ct < 8; ++ct){
    #pragma unroll
    for (int q = 0; q < 4; ++q)
      Cst[(wid*16 + 4*g + q)*132 + ct*16 + r] = acc[ct][q];
  }
  __syncthreads();
  {
    int row = tid >> 2, hd = tid & 3;
    int grow = base + row;
    if (grow < N_NODES){
      const float* cp = &Cst[row*132 + hd*32];
      const float* aS = attS + hd*32;
      const float* aD = attD + hd*32;
      float ps = 0.f, pd = 0.f;
      unsigned u[8];
      #pragma unroll
      for (int i = 0; i < 8; ++i){
        float4 c4 = *(const float4*)(cp + 4*i);
        ps += c4.x*aS[4*i] + c4.y*aS[4*i+1] + c4.z*aS[4*i+2] + c4.w*aS[4*i+3];
        pd += c4.x*aD[4*i] + c4.y*aD[4*i+1] + c4.z*aD[4*i+2] + c4.w*aD[4*i+3];
        u[i] = pack_fp8x4(c4);
      }
      unsigned* dst = h1f + (size_t)grow*32 + hd*8;
      *(uint4*)(dst)     = make_uint4(u[0], u[1], u[2], u[3]);
      *(uint4*)(dst + 4) = make_uint4(u[4], u[5], u[6], u[7]);
      asrc[grow*4 + hd] = ps;
      adst[grow*4 + hd] = pd;
    }
  }
}

__global__ __launch_bounds__(256) void k_csr(const unsigned* __restrict__ basev,
    const unsigned* __restrict__ staging, unsigned* __restrict__ off,
    int* __restrict__ csr_src){
  __shared__ unsigned ts[256], cur[256];
  int tid = threadIdx.x, b = blockIdx.x;
  unsigned start = basev[b*NCHUNK];
  unsigned end = (b == NBUCK-1) ? (unsigned)ETOT : basev[(b+1)*NCHUNK];
  ts[tid] = 0;
  __syncthreads();
  for (unsigned i = start + tid; i < end; i += 256)
    atomicAdd(&ts[staging[i] >> 16], 1u);
  __syncthreads();
  unsigned v = ts[tid];
  for (int o = 1; o < 256; o <<= 1){
    unsigned u = (tid >= o) ? ts[tid-o] : 0u;
    __syncthreads();
    ts[tid] += u;
    __syncthreads();
  }
  unsigned excl = ts[tid] - v;
  int node = (b << 8) + tid;
  if (node < N_NODES) off[node] = start + excl;
  if (b == 0 && tid == 0) off[N_NODES] = (unsigned)ETOT;
  cur[tid] = excl;
  __syncthreads();
  for (unsigned i = start + tid; i < end; i += 256){
    unsigned p = staging[i];
    unsigned pos = atomicAdd(&cur[p >> 16], 1u);
    csr_src[start + pos] = (int)(p & 0xffffu);
  }
}

// ---------------- conv1: wave/node; fp8 rows, no max-subtraction -----------------------
__global__ __launch_bounds__(256) void k_conv1(const unsigned* __restrict__ off,
    const int* __restrict__ csr_src, const unsigned* __restrict__ h1f,
    const float* __restrict__ asrc, const float* __restrict__ adst,
    const float* __restrict__ b1, unsigned* __restrict__ helu_b)
{
  __shared__ uint2 st[4][4][66];  // [wave][head][edge] = {exp_bits, row_byte_off}
  int w    = threadIdx.x >> 6;
  int lane = threadIdx.x & 63;
  int n = blockIdx.x*4 + w;
  if (n >= N_NODES) return;
  unsigned s0 = off[n];
  int deg = (int)(off[n+1] - s0);
  float4 ad = *(const float4*)(adst + (size_t)n*4);
  int cl = lane & 31;             // feature slot: features 4*cl..4*cl+3
  int h  = cl >> 3;               // head of this slot
  const char* hbase = (const char*)h1f + 4*cl;
  float4 acc = make_float4(0,0,0,0);
  float den = 0.f;

  if (deg <= 64){
    unsigned boff = 0;
    float e0=0.f, e1=0.f, e2=0.f, e3=0.f;
    if (lane < deg){
      int idx = csr_src[s0 + lane];
      boff = ((unsigned)idx) << 7;          // 128 B fp8 row
      float4 as = *(const float4*)(asrc + (size_t)idx*4);
      e0 = __expf(leaky02(as.x + ad.x));
      e1 = __expf(leaky02(as.y + ad.y));
      e2 = __expf(leaky02(as.z + ad.z));
      e3 = __expf(leaky02(as.w + ad.w));
    }
    st[w][0][lane] = make_uint2(__float_as_uint(e0), boff);
    st[w][1][lane] = make_uint2(__float_as_uint(e1), boff);
    st[w][2][lane] = make_uint2(__float_as_uint(e2), boff);
    st[w][3][lane] = make_uint2(__float_as_uint(e3), boff);
    __builtin_amdgcn_wave_barrier();        // wave-coherent LDS, no s_barrier
    int half = lane >> 5;
    const uint2* sp = &st[w][h][half];
    #pragma unroll 8
    for (int i = 0; i < deg; i += 2){
      uint2 p = sp[i];
      float es = __uint_as_float(p.x);
      unsigned hb = *(const unsigned*)(hbase + p.y);
      vf2 p0 = __builtin_amdgcn_cvt_pk_f32_fp8((int)hb, false);
      vf2 p1 = __builtin_amdgcn_cvt_pk_f32_fp8((int)hb, true);
      acc.x += es*p0[0]; acc.y += es*p0[1];
      acc.z += es*p1[0]; acc.w += es*p1[1];
      den += es;
    }
    acc.x += __shfl_xor(acc.x, 32); acc.y += __shfl_xor(acc.y, 32);
    acc.z += __shfl_xor(acc.z, 32); acc.w += __shfl_xor(acc.w, 32);
    den   += __shfl_xor(den, 32);
  } else {
    float adh = (h==0) ? ad.x : (h==1) ? ad.y : (h==2) ? ad.z : ad.w;
    for (int i = 0; i < deg; ++i){
      int s = csr_src[s0 + i];
      float ev = __expf(leaky02(asrc[s*4 + h] + adh));
      unsigned hb = *(const unsigned*)(hbase + (((unsigned)s) << 7));
      vf2 p0 = __builtin_amdgcn_cvt_pk_f32_fp8((int)hb, false);
      vf2 p1 = __builtin_amdgcn_cvt_pk_f32_fp8((int)hb, true);
      acc.x += ev*p0[0]; acc.y += ev*p0[1];
      acc.z += ev*p1[0]; acc.w += ev*p1[1];
      den += ev;
    }
  }
  if (lane < 32){
    float inv = 1.f/(den + 1e-16f);
    float4 bv = ((const float4*)b1)[cl];
    float ox = eluf(acc.x*inv + bv.x), oy = eluf(acc.y*inv + bv.y);
    float oz = eluf(acc.z*inv + bv.z), ow = eluf(acc.w*inv + bv.w);
    *(uint2*)(helu_b + (size_t)n*64 + 2*cl) = make_uint2(pack_bf16(ox, oy), pack_bf16(oz, ow));
  }
}

// ---------------- GEMM2 (MFMA bf16): h2 = helu @ W2, h2 -> bf16; scalar alphas ---------
__global__ __launch_bounds__(256) void k_gemm2(const unsigned* __restrict__ helu_b,
    const unsigned* __restrict__ wt2, const float* __restrict__ attS,
    const float* __restrict__ attD, unsigned* __restrict__ h2b,
    float* __restrict__ asrc, float* __restrict__ adst)
{
  __shared__ __align__(16) short xs[64*136];    // 17.4 KB
  __shared__ __align__(16) float cbuf[64*36];   // 9.2 KB f32; first 8.7 KB doubles as Wt2
  short* w2 = (short*)cbuf;
  int tid = threadIdx.x;
  int base = blockIdx.x * 64;
  {
    int row = tid >> 2, q = tid & 3;
    bool valid = (base + row) < N_NODES;
    const unsigned* src = helu_b + (size_t)(base + row)*64 + q*16;
    #pragma unroll
    for (int i = 0; i < 4; ++i){
      uint4 v = valid ? *(const uint4*)(src + 4*i) : make_uint4(0,0,0,0);
      *(uint4*)(&xs[row*136 + q*32 + 8*i]) = v;
    }
  }
  {
    int c = tid >> 3, h = tid & 7;
    uint4 v0 = *(const uint4*)(wt2 + c*64 + h*8);
    uint4 v1 = *(const uint4*)(wt2 + c*64 + h*8 + 4);
    *(uint4*)(&w2[c*136 + h*16])     = v0;
    *(uint4*)(&w2[c*136 + h*16 + 8]) = v1;
  }
  __syncthreads();
  int lane = tid & 63, wid = tid >> 6;
  int r = lane & 15, g = lane >> 4;
  bf16x8 afr[4];
  #pragma unroll
  for (int kk = 0; kk < 4; ++kk)
    afr[kk] = *(const bf16x8*)(&xs[(wid*16 + r)*136 + kk*32 + g*8]);
  f32x4 acc[2];
  #pragma unroll
  for (int ct = 0; ct < 2; ++ct){ acc[ct][0]=0.f; acc[ct][1]=0.f; acc[ct][2]=0.f; acc[ct][3]=0.f; }
  #pragma unroll
  for (int ct = 0; ct < 2; ++ct){
    #pragma unroll
    for (int kk = 0; kk < 4; ++kk){
      bf16x8 bfr = *(const bf16x8*)(&w2[(ct*16 + r)*136 + kk*32 + g*8]);
      acc[ct] = __builtin_amdgcn_mfma_f32_16x16x32_bf16(afr[kk], bfr, acc[ct], 0, 0, 0);
    }
  }
  __syncthreads();
  #pragma unroll
  for (int ct = 0; ct < 2; ++ct){
    #pragma unroll
    for (int q = 0; q < 4; ++q)
      cbuf[(wid*16 + 4*g + q)*36 + ct*16 + r] = acc[ct][q];
  }
  __syncthreads();
  {
    int row = tid >> 2, q = tid & 3;
    int grow = base + row;
    if (grow < N_NODES){
      const float* cp = &cbuf[row*36 + q*8];
      float4 c0 = *(const float4*)(cp);
      float4 c1 = *(const float4*)(cp + 4);
      *(uint4*)(h2b + (size_t)grow*16 + q*4) =
        make_uint4(pack_bf16(c0.x,c0.y), pack_bf16(c0.z,c0.w),
                   pack_bf16(c1.x,c1.y), pack_bf16(c1.z,c1.w));
    }
  }
  if (tid < 64){
    int grow = base + tid;
    if (grow < N_NODES){
      const float* cp = &cbuf[tid*36];
      float ps = 0.f, pd = 0.f;
      #pragma unroll
      for (int i = 0; i < 8; ++i){
        float4 c4 = *(const float4*)(cp + 4*i);
        ps += c4.x*attS[4*i] + c4.y*attS[4*i+1] + c4.z*attS[4*i+2] + c4.w*attS[4*i+3];
        pd += c4.x*attD[4*i] + c4.y*attD[4*i+1] + c4.z*attD[4*i+2] + c4.w*attD[4*i+3];
      }
      asrc[grow] = ps; adst[grow] = pd;
    }
  }
}

// ---------------- conv2: wave/node; bf16 rows, no max-subtraction ----------------------
__global__ __launch_bounds__(256) void k_conv2(const unsigned* __restrict__ off,
    const int* __restrict__ csr_src, const unsigned* __restrict__ h2b,
    const float* __restrict__ asrc, const float* __restrict__ adst,
    const float* __restrict__ b2, float* __restrict__ hout)
{
  __shared__ uint2 st[4][66];     // {exp_bits, row_byte_off}
  int w    = threadIdx.x >> 6;
  int lane = threadIdx.x & 63;
  int n = blockIdx.x*4 + w;
  if (n >= N_NODES) return;
  unsigned s0 = off[n];
  int deg = (int)(off[n+1] - s0);
  float ad = adst[n];
  int cl = lane & 7;              // feature slot: floats 4*cl..4*cl+3
  const char* hbase = (const char*)h2b + 8*cl;
  float4 acc = make_float4(0,0,0,0);
  float den = 0.f;

  if (deg <= 64){
    unsigned boff = 0;
    float e = 0.f;
    if (lane < deg){
      int idx = csr_src[s0 + lane];
      boff = ((unsigned)idx) << 6;          // 64 B bf16 row
      e = __expf(leaky02(asrc[idx] + ad));
    }
    st[w][lane] = make_uint2(__float_as_uint(e), boff);
    __builtin_amdgcn_wave_barrier();
    int g8 = lane >> 3;
    const uint2* sp = &st[w][g8];
    #pragma unroll 4
    for (int i = 0; i < deg; i += 8){
      uint2 p = sp[i];
      float es = __uint_as_float(p.x);
      uint2 hb = *(const uint2*)(hbase + p.y);
      acc.x += es*bf_lo(hb.x); acc.y += es*bf_hi(hb.x);
      acc.z += es*bf_lo(hb.y); acc.w += es*bf_hi(hb.y);
      den += es;
    }
    #pragma unroll
    for (int mm = 8; mm <= 32; mm <<= 1){
      acc.x += __shfl_xor(acc.x, mm); acc.y += __shfl_xor(acc.y, mm);
      acc.z += __shfl_xor(acc.z, mm); acc.w += __shfl_xor(acc.w, mm);
      den   += __shfl_xor(den, mm);
    }
  } else {
    for (int i = 0; i < deg; ++i){
      int s = csr_src[s0 + i];
      float ev = __expf(leaky02(asrc[s] + ad));
      uint2 hb = *(const uint2*)(hbase + (((unsigned)s) << 6));
      acc.x += ev*bf_lo(hb.x); acc.y += ev*bf_hi(hb.x);
      acc.z += ev*bf_lo(hb.y); acc.w += ev*bf_hi(hb.y);
      den += ev;
    }
  }
  if (lane < 8){
    float inv = 1.f/(den + 1e-16f);
    float4 bv = ((const float4*)b2)[cl];
    float4 o;
    o.x = acc.x*inv + bv.x; o.y = acc.y*inv + bv.y;
    o.z = acc.z*inv + bv.z; o.w = acc.w*inv + bv.w;
    *(float4*)(hout + (size_t)n*32 + 4*cl) = o;
  }
}

// ---------------- pool: 8 blocks per graph -> deterministic partials + gcnt ------------
__global__ __launch_bounds__(256) void k_pool(const int* __restrict__ batch,
    const float* __restrict__ hout, float* __restrict__ gpart, int* __restrict__ gcnt)
{
  int g = blockIdx.x >> 3, sub = blockIdx.x & 7;
  int a = 0, b = N_NODES;
  while (a < b){ int mid = (a+b)>>1; if (batch[mid] < g) a = mid+1; else b = mid; }
  int lo = a;
  b = N_NODES;
  while (a < b){ int mid = (a+b)>>1; if (batch[mid] < g+1) a = mid+1; else b = mid; }
  int hi = a;
  if (sub == 0 && threadIdx.x == 0) gcnt[g] = hi - lo;
  int c = threadIdx.x & 31, rg = threadIdx.x >> 5;   // 8 row groups
  float s = 0.f;
  for (int r = lo + sub*8 + rg; r < hi; r += 64) s += hout[(size_t)r*32 + c];
  __shared__ float red[8][32];
  red[rg][c] = s;
  __syncthreads();
  if (rg == 0){
    float t = 0.f;
    #pragma unroll
    for (int k = 0; k < 8; ++k) t += red[k][c];
    gpart[(size_t)blockIdx.x*32 + c] = t;
  }
}

// ---------------- final: sum partials (float4), mean, MLP (64 graphs, 1 block) ---------
__global__ void k_final(const int* __restrict__ gcnt, const float* __restrict__ gpart,
    const float* __restrict__ l1w, const float* __restrict__ l1b,
    const float* __restrict__ l2w, const float* __restrict__ l2b, float* __restrict__ out)
{
  int t = threadIdx.x;
  if (t >= NG) return;
  float cinv = 1.f / fmaxf((float)gcnt[t], 1.0f);
  float4 gs[8];
  #pragma unroll
  for (int q = 0; q < 8; ++q) gs[q] = make_float4(0,0,0,0);
  #pragma unroll
  for (int p = 0; p < 8; ++p){
    const float4* pp = (const float4*)(gpart + (size_t)(t*8 + p)*32);
    #pragma unroll
    for (int q = 0; q < 8; ++q){
      float4 v = pp[q];
      gs[q].x += v.x; gs[q].y += v.y; gs[q].z += v.z; gs[q].w += v.w;
    }
  }
  float g[32];
  #pragma unroll
  for (int q = 0; q < 8; ++q){
    g[4*q]   = gs[q].x * cinv; g[4*q+1] = gs[q].y * cinv;
    g[4*q+2] = gs[q].z * cinv; g[4*q+3] = gs[q].w * cinv;
  }
  float o = l2b[0];
  #pragma unroll
  for (int k = 0; k < 16; ++k){
    float hv = l1b[k];
    #pragma unroll
    for (int j = 0; j < 32; ++j) hv += g[j]*l1w[j*16 + k];
    o += eluf(hv) * l2w[k];
  }
  out[t] = o;
}

extern "C" void kernel_launch(void* const* d_in, const int* in_sizes, int n_in,
                              void* d_out, int out_size, void* d_ws, size_t ws_size,
                              hipStream_t stream) {
  const float* x     = (const float*)d_in[0];
  const int*   ei    = (const int*)  d_in[1];
  const int*   batch = (const int*)  d_in[2];
  const float* W1    = (const float*)d_in[3];
  const float* attS1 = (const float*)d_in[4];
  const float* attD1 = (const float*)d_in[5];
  const float* b1    = (const float*)d_in[6];
  const float* W2    = (const float*)d_in[7];
  const float* attS2 = (const float*)d_in[8];
  const float* attD2 = (const float*)d_in[9];
  const float* b2    = (const float*)d_in[10];
  const float* l1w   = (const float*)d_in[11];
  const float* l1b   = (const float*)d_in[12];
  const float* l2w   = (const float*)d_in[13];
  const float* l2b   = (const float*)d_in[14];
  float* out = (float*)d_out;

  char* w = (char*)d_ws;
  auto alloc = [&](size_t elems) -> void* {
    void* p = (void*)w;
    w += ((elems*4 + 255)/256)*256;
    return p;
  };
  unsigned* csr_off = (unsigned*)alloc(N_NODES + 1);
  unsigned* cnt     = (unsigned*)alloc(SCANN);
  unsigned* basev   = (unsigned*)alloc(SCANN);
  unsigned* staging = (unsigned*)alloc(ETOT);
  int*      csr_src = (int*)     alloc(ETOT);
  unsigned* wt1g  = (unsigned*)alloc(128*64);               // bf16 W1^T [128c][128k]
  unsigned* wt2g  = (unsigned*)alloc(32*64);                // bf16 W2^T [32c][128k]
  unsigned* h1f   = (unsigned*)alloc((size_t)N_NODES*32);   // fp8-packed [N,128]
  float*    asrc1 = (float*)alloc((size_t)N_NODES*4);
  float*    adst1 = (float*)alloc((size_t)N_NODES*4);
  unsigned* helu_b= (unsigned*)alloc((size_t)N_NODES*64);   // bf16-packed [N,128]
  unsigned* h2b   = (unsigned*)alloc((size_t)N_NODES*16);   // bf16-packed [N,32]
  float*    asrc2 = (float*)alloc(N_NODES);
  float*    adst2 = (float*)alloc(N_NODES);
  float*    hout  = (float*)alloc((size_t)N_NODES*32);
  float*    gpart = (float*)alloc(NG*8*32);
  int*      gcnt  = (int*)alloc(NG);

  k_hist  <<<NCHUNK + 160, 256, 0, stream>>>(ei, cnt, W1, W2, wt1g, wt2g);
  g_scanM <<<GSB, 256, 0, stream>>>(cnt, basev, SCANN);
  k_pg    <<<NCHUNK + GB1, 256, 0, stream>>>(ei, basev, staging,
                                             x, wt1g, attS1, attD1, h1f, asrc1, adst1);
  k_csr   <<<NBUCK, 256, 0, stream>>>(basev, staging, csr_off, csr_src);

  k_conv1<<<(N_NODES + 3)/4, 256, 0, stream>>>(csr_off, csr_src, h1f, asrc1, adst1, b1, helu_b);
  k_gemm2<<<(N_NODES + 63)/64, 256, 0, stream>>>(helu_b, wt2g, attS2, attD2, h2b, asrc2, adst2);
  k_conv2<<<(N_NODES + 3)/4, 256, 0, stream>>>(csr_off, csr_src, h2b, asrc2, adst2, b2, hout);
  k_pool <<<NG*8, 256, 0, stream>>>(batch, hout, gpart, gcnt);
  k_final<<<1, 64, 0, stream>>>(gcnt, gpart, l1w, l1b, l2w, l2b, out);
}

// Round 19
// 130.173 us; speedup vs baseline: 1.3914x; 1.1864x over previous
//
#include <hip/hip_runtime.h>
#include <math.h>

#define N_NODES 50000
#define N_EDGES 800000
#define ETOT (N_EDGES + N_NODES)
#define NG 64
#define NBUCK 196                 // dst buckets of 256 nodes
#define CHUNK 4096
#define NCHUNK ((ETOT + CHUNK - 1)/CHUNK)   // 208
#define CAP 5120                  // slots per bucket (mean 4352, sigma 64 -> 12 sigma)
#define GB1 ((N_NODES + 63)/64)   // 782 gemm1 blocks

typedef float vf2 __attribute__((ext_vector_type(2)));
typedef short bf16x8 __attribute__((ext_vector_type(8)));
typedef float f32x4 __attribute__((ext_vector_type(4)));

__device__ __forceinline__ float leaky02(float a){ return a > 0.f ? a : 0.2f*a; }
__device__ __forceinline__ float eluf(float v){ return v > 0.f ? v : expm1f(v); }

// round-to-nearest-even f32->bf16, packed pair (a low, b high)
__device__ __forceinline__ unsigned pack_bf16(float a, float b){
  unsigned ua = __float_as_uint(a); ua += 0x7fffu + ((ua >> 16) & 1u);
  unsigned ub = __float_as_uint(b); ub += 0x7fffu + ((ub >> 16) & 1u);
  return (ua >> 16) | (ub & 0xffff0000u);
}
__device__ __forceinline__ float bf_lo(unsigned v){ return __uint_as_float(v << 16); }
__device__ __forceinline__ float bf_hi(unsigned v){ return __uint_as_float(v & 0xffff0000u); }

// fp8 e4m3 pack via HW cvt (self-consistent internal format)
__device__ __forceinline__ unsigned pack_fp8x4(float4 a){
  int v = __builtin_amdgcn_cvt_pk_fp8_f32(a.x, a.y, 0, false);
  v = __builtin_amdgcn_cvt_pk_fp8_f32(a.z, a.w, v, true);
  return (unsigned)v;
}

// ---------------- kernel A: edge partition (hist + reserve + scatter) || weight prep ---
__global__ __launch_bounds__(256) void k_partA(const int* __restrict__ ei,
    unsigned* __restrict__ gcur, unsigned* __restrict__ staging,
    const float* __restrict__ W1, const float* __restrict__ W2,
    unsigned* __restrict__ wt1, unsigned* __restrict__ wt2){
  if (blockIdx.x >= NCHUNK){
    int b = blockIdx.x - NCHUNK;   // 0..159
    int t = threadIdx.x;
    if (t < 64){
      if (b < 128){
        float a = W1[(size_t)(2*t)*128 + b];
        float c = W1[(size_t)(2*t+1)*128 + b];
        wt1[b*64 + t] = pack_bf16(a, c);
      } else {
        int cc = b - 128;
        float a = W2[(size_t)(2*t)*32 + cc];
        float c = W2[(size_t)(2*t+1)*32 + cc];
        wt2[cc*64 + t] = pack_bf16(a, c);
      }
    }
    return;
  }
  __shared__ unsigned hist[NBUCK], cur[NBUCK];
  int tid = threadIdx.x;
  for (int t = tid; t < NBUCK; t += 256) hist[t] = 0;
  __syncthreads();
  int base = blockIdx.x * CHUNK;
  #pragma unroll
  for (int i = 0; i < CHUNK/256; ++i){
    int e = base + i*256 + tid;
    if (e < ETOT){
      int d = (e < N_EDGES) ? ei[N_EDGES + e] : (e - N_EDGES);
      atomicAdd(&hist[d >> 8], 1u);
    }
  }
  __syncthreads();
  for (int t = tid; t < NBUCK; t += 256)
    cur[t] = atomicAdd(&gcur[t], hist[t]);   // reserve contiguous run in bucket
  __syncthreads();
  #pragma unroll
  for (int i = 0; i < CHUNK/256; ++i){
    int e = base + i*256 + tid;
    if (e < ETOT){
      int s, d;
      if (e < N_EDGES){ s = ei[e]; d = ei[N_EDGES + e]; } else { s = d = e - N_EDGES; }
      int bk = d >> 8;
      unsigned pos = atomicAdd(&cur[bk], 1u);
      staging[(size_t)bk*CAP + pos] = (unsigned)s | ((unsigned)(d & 255) << 16);
    }
  }
}

// ---------------- kernel B: per-bucket CSR finalize (196) || GEMM1 (782) ---------------
__global__ __launch_bounds__(256) void k_cg(const unsigned* __restrict__ gcur,
    const unsigned* __restrict__ staging, uint2* __restrict__ nfo, int* __restrict__ csr_src,
    const float* __restrict__ x, const unsigned* __restrict__ wt1,
    const float* __restrict__ attS, const float* __restrict__ attD,
    unsigned* __restrict__ h1f, float* __restrict__ asrc, float* __restrict__ adst)
{
  __shared__ unsigned ts[256], cur2[256];
  __shared__ __align__(16) short xs[64*136];    // 17.4 KB bf16
  __shared__ __align__(16) short wb[128*136];   // 34.8 KB bf16; reused as Cst f32 [64][132]
  int tid = threadIdx.x;

  if (blockIdx.x < NBUCK){
    // ---- CSR finalize for bucket b ----
    int b = blockIdx.x;
    unsigned count = gcur[b];
    unsigned sbase = (unsigned)b*CAP;
    ts[tid] = 0;
    __syncthreads();
    for (unsigned i = tid; i < count; i += 256)
      atomicAdd(&ts[staging[sbase + i] >> 16], 1u);
    __syncthreads();
    unsigned v = ts[tid];
    for (int o = 1; o < 256; o <<= 1){
      unsigned u = (tid >= o) ? ts[tid-o] : 0u;
      __syncthreads();
      ts[tid] += u;
      __syncthreads();
    }
    unsigned excl = ts[tid] - v;
    int node = (b << 8) + tid;
    if (node < N_NODES) nfo[node] = make_uint2(sbase + excl, v);
    cur2[tid] = excl;
    __syncthreads();
    for (unsigned i = tid; i < count; i += 256){
      unsigned p = staging[sbase + i];
      unsigned pos = atomicAdd(&cur2[p >> 16], 1u);
      csr_src[sbase + pos] = (int)(p & 0xffffu);
    }
    return;
  }

  // ---- GEMM1 (MFMA bf16): h1 = x @ W1 -> fp8; alphas from f32 acc ----
  float* Cst = (float*)wb;
  int base = (blockIdx.x - NBUCK) * 64;
  {
    int row = tid >> 2, q = tid & 3;
    const float* src = x + (size_t)(base + row)*128 + q*32;
    bool valid = (base + row) < N_NODES;
    #pragma unroll
    for (int i = 0; i < 8; ++i){
      float4 v = valid ? *(const float4*)(src + 4*i) : make_float4(0,0,0,0);
      *(uint2*)(&xs[row*136 + q*32 + 4*i]) = make_uint2(pack_bf16(v.x, v.y), pack_bf16(v.z, v.w));
    }
  }
  {
    int c = tid >> 1, h = tid & 1;
    #pragma unroll
    for (int i = 0; i < 8; ++i){
      uint4 v = *(const uint4*)(wt1 + c*64 + h*32 + 4*i);
      *(uint4*)(&wb[c*136 + h*64 + 8*i]) = v;
    }
  }
  __syncthreads();
  int lane = tid & 63, wid = tid >> 6;
  int r = lane & 15, g = lane >> 4;
  bf16x8 afr[4];
  #pragma unroll
  for (int kk = 0; kk < 4; ++kk)
    afr[kk] = *(const bf16x8*)(&xs[(wid*16 + r)*136 + kk*32 + g*8]);
  f32x4 acc[8];
  #pragma unroll
  for (int ct = 0; ct < 8; ++ct){ acc[ct][0]=0.f; acc[ct][1]=0.f; acc[ct][2]=0.f; acc[ct][3]=0.f; }
  #pragma unroll
  for (int ct = 0; ct < 8; ++ct){
    #pragma unroll
    for (int kk = 0; kk < 4; ++kk){
      bf16x8 bfr = *(const bf16x8*)(&wb[(ct*16 + r)*136 + kk*32 + g*8]);
      acc[ct] = __builtin_amdgcn_mfma_f32_16x16x32_bf16(afr[kk], bfr, acc[ct], 0, 0, 0);
    }
  }
  __syncthreads();   // everyone done reading wb; reuse as Cst
  #pragma unroll
  for (int ct = 0; ct < 8; ++ct){
    #pragma unroll
    for (int q = 0; q < 4; ++q)
      Cst[(wid*16 + 4*g + q)*132 + ct*16 + r] = acc[ct][q];
  }
  __syncthreads();
  {
    int row = tid >> 2, hd = tid & 3;
    int grow = base + row;
    if (grow < N_NODES){
      const float* cp = &Cst[row*132 + hd*32];
      const float* aS = attS + hd*32;
      const float* aD = attD + hd*32;
      float ps = 0.f, pd = 0.f;
      unsigned u[8];
      #pragma unroll
      for (int i = 0; i < 8; ++i){
        float4 c4 = *(const float4*)(cp + 4*i);
        ps += c4.x*aS[4*i] + c4.y*aS[4*i+1] + c4.z*aS[4*i+2] + c4.w*aS[4*i+3];
        pd += c4.x*aD[4*i] + c4.y*aD[4*i+1] + c4.z*aD[4*i+2] + c4.w*aD[4*i+3];
        u[i] = pack_fp8x4(c4);
      }
      unsigned* dst = h1f + (size_t)grow*32 + hd*8;
      *(uint4*)(dst)     = make_uint4(u[0], u[1], u[2], u[3]);
      *(uint4*)(dst + 4) = make_uint4(u[4], u[5], u[6], u[7]);
      asrc[grow*4 + hd] = ps;
      adst[grow*4 + hd] = pd;
    }
  }
}

// ---------------- conv1: wave/node; fp8 rows, no max-subtraction -----------------------
__global__ __launch_bounds__(256) void k_conv1(const uint2* __restrict__ nfo,
    const int* __restrict__ csr_src, const unsigned* __restrict__ h1f,
    const float* __restrict__ asrc, const float* __restrict__ adst,
    const float* __restrict__ b1, unsigned* __restrict__ helu_b)
{
  __shared__ uint2 st[4][4][66];  // [wave][head][edge] = {exp_bits, row_byte_off}
  int w    = threadIdx.x >> 6;
  int lane = threadIdx.x & 63;
  int n = blockIdx.x*4 + w;
  if (n >= N_NODES) return;
  uint2 nf = nfo[n];
  unsigned s0 = nf.x;
  int deg = (int)nf.y;
  float4 ad = *(const float4*)(adst + (size_t)n*4);
  int cl = lane & 31;             // feature slot: features 4*cl..4*cl+3
  int h  = cl >> 3;               // head of this slot
  const char* hbase = (const char*)h1f + 4*cl;
  float4 acc = make_float4(0,0,0,0);
  float den = 0.f;

  if (deg <= 64){
    unsigned boff = 0;
    float e0=0.f, e1=0.f, e2=0.f, e3=0.f;
    if (lane < deg){
      int idx = csr_src[s0 + lane];
      boff = ((unsigned)idx) << 7;          // 128 B fp8 row
      float4 as = *(const float4*)(asrc + (size_t)idx*4);
      e0 = __expf(leaky02(as.x + ad.x));
      e1 = __expf(leaky02(as.y + ad.y));
      e2 = __expf(leaky02(as.z + ad.z));
      e3 = __expf(leaky02(as.w + ad.w));
    }
    st[w][0][lane] = make_uint2(__float_as_uint(e0), boff);
    st[w][1][lane] = make_uint2(__float_as_uint(e1), boff);
    st[w][2][lane] = make_uint2(__float_as_uint(e2), boff);
    st[w][3][lane] = make_uint2(__float_as_uint(e3), boff);
    __builtin_amdgcn_wave_barrier();        // wave-coherent LDS, no s_barrier
    int half = lane >> 5;
    const uint2* sp = &st[w][h][half];
    #pragma unroll 8
    for (int i = 0; i < deg; i += 2){
      uint2 p = sp[i];
      float es = __uint_as_float(p.x);
      unsigned hb = *(const unsigned*)(hbase + p.y);
      vf2 p0 = __builtin_amdgcn_cvt_pk_f32_fp8((int)hb, false);
      vf2 p1 = __builtin_amdgcn_cvt_pk_f32_fp8((int)hb, true);
      acc.x += es*p0[0]; acc.y += es*p0[1];
      acc.z += es*p1[0]; acc.w += es*p1[1];
      den += es;
    }
    acc.x += __shfl_xor(acc.x, 32); acc.y += __shfl_xor(acc.y, 32);
    acc.z += __shfl_xor(acc.z, 32); acc.w += __shfl_xor(acc.w, 32);
    den   += __shfl_xor(den, 32);
  } else {
    float adh = (h==0) ? ad.x : (h==1) ? ad.y : (h==2) ? ad.z : ad.w;
    for (int i = 0; i < deg; ++i){
      int s = csr_src[s0 + i];
      float ev = __expf(leaky02(asrc[s*4 + h] + adh));
      unsigned hb = *(const unsigned*)(hbase + (((unsigned)s) << 7));
      vf2 p0 = __builtin_amdgcn_cvt_pk_f32_fp8((int)hb, false);
      vf2 p1 = __builtin_amdgcn_cvt_pk_f32_fp8((int)hb, true);
      acc.x += ev*p0[0]; acc.y += ev*p0[1];
      acc.z += ev*p1[0]; acc.w += ev*p1[1];
      den += ev;
    }
  }
  if (lane < 32){
    float inv = 1.f/(den + 1e-16f);
    float4 bv = ((const float4*)b1)[cl];
    float ox = eluf(acc.x*inv + bv.x), oy = eluf(acc.y*inv + bv.y);
    float oz = eluf(acc.z*inv + bv.z), ow = eluf(acc.w*inv + bv.w);
    *(uint2*)(helu_b + (size_t)n*64 + 2*cl) = make_uint2(pack_bf16(ox, oy), pack_bf16(oz, ow));
  }
}

// ---------------- GEMM2 (MFMA bf16): h2 = helu @ W2, h2 -> bf16; scalar alphas ---------
__global__ __launch_bounds__(256) void k_gemm2(const unsigned* __restrict__ helu_b,
    const unsigned* __restrict__ wt2, const float* __restrict__ attS,
    const float* __restrict__ attD, unsigned* __restrict__ h2b,
    float* __restrict__ asrc, float* __restrict__ adst)
{
  __shared__ __align__(16) short xs[64*136];    // 17.4 KB
  __shared__ __align__(16) float cbuf[64*36];   // 9.2 KB f32; first 8.7 KB doubles as Wt2
  short* w2 = (short*)cbuf;
  int tid = threadIdx.x;
  int base = blockIdx.x * 64;
  {
    int row = tid >> 2, q = tid & 3;
    bool valid = (base + row) < N_NODES;
    const unsigned* src = helu_b + (size_t)(base + row)*64 + q*16;
    #pragma unroll
    for (int i = 0; i < 4; ++i){
      uint4 v = valid ? *(const uint4*)(src + 4*i) : make_uint4(0,0,0,0);
      *(uint4*)(&xs[row*136 + q*32 + 8*i]) = v;
    }
  }
  {
    int c = tid >> 3, h = tid & 7;
    uint4 v0 = *(const uint4*)(wt2 + c*64 + h*8);
    uint4 v1 = *(const uint4*)(wt2 + c*64 + h*8 + 4);
    *(uint4*)(&w2[c*136 + h*16])     = v0;
    *(uint4*)(&w2[c*136 + h*16 + 8]) = v1;
  }
  __syncthreads();
  int lane = tid & 63, wid = tid >> 6;
  int r = lane & 15, g = lane >> 4;
  bf16x8 afr[4];
  #pragma unroll
  for (int kk = 0; kk < 4; ++kk)
    afr[kk] = *(const bf16x8*)(&xs[(wid*16 + r)*136 + kk*32 + g*8]);
  f32x4 acc[2];
  #pragma unroll
  for (int ct = 0; ct < 2; ++ct){ acc[ct][0]=0.f; acc[ct][1]=0.f; acc[ct][2]=0.f; acc[ct][3]=0.f; }
  #pragma unroll
  for (int ct = 0; ct < 2; ++ct){
    #pragma unroll
    for (int kk = 0; kk < 4; ++kk){
      bf16x8 bfr = *(const bf16x8*)(&w2[(ct*16 + r)*136 + kk*32 + g*8]);
      acc[ct] = __builtin_amdgcn_mfma_f32_16x16x32_bf16(afr[kk], bfr, acc[ct], 0, 0, 0);
    }
  }
  __syncthreads();
  #pragma unroll
  for (int ct = 0; ct < 2; ++ct){
    #pragma unroll
    for (int q = 0; q < 4; ++q)
      cbuf[(wid*16 + 4*g + q)*36 + ct*16 + r] = acc[ct][q];
  }
  __syncthreads();
  {
    int row = tid >> 2, q = tid & 3;
    int grow = base + row;
    if (grow < N_NODES){
      const float* cp = &cbuf[row*36 + q*8];
      float4 c0 = *(const float4*)(cp);
      float4 c1 = *(const float4*)(cp + 4);
      *(uint4*)(h2b + (size_t)grow*16 + q*4) =
        make_uint4(pack_bf16(c0.x,c0.y), pack_bf16(c0.z,c0.w),
                   pack_bf16(c1.x,c1.y), pack_bf16(c1.z,c1.w));
    }
  }
  if (tid < 64){
    int grow = base + tid;
    if (grow < N_NODES){
      const float* cp = &cbuf[tid*36];
      float ps = 0.f, pd = 0.f;
      #pragma unroll
      for (int i = 0; i < 8; ++i){
        float4 c4 = *(const float4*)(cp + 4*i);
        ps += c4.x*attS[4*i] + c4.y*attS[4*i+1] + c4.z*attS[4*i+2] + c4.w*attS[4*i+3];
        pd += c4.x*attD[4*i] + c4.y*attD[4*i+1] + c4.z*attD[4*i+2] + c4.w*attD[4*i+3];
      }
      asrc[grow] = ps; adst[grow] = pd;
    }
  }
}

// ---------------- conv2: wave/node; bf16 rows, no max-subtraction ----------------------
__global__ __launch_bounds__(256) void k_conv2(const uint2* __restrict__ nfo,
    const int* __restrict__ csr_src, const unsigned* __restrict__ h2b,
    const float* __restrict__ asrc, const float* __restrict__ adst,
    const float* __restrict__ b2, float* __restrict__ hout)
{
  __shared__ uint2 st[4][66];     // {exp_bits, row_byte_off}
  int w    = threadIdx.x >> 6;
  int lane = threadIdx.x & 63;
  int n = blockIdx.x*4 + w;
  if (n >= N_NODES) return;
  uint2 nf = nfo[n];
  unsigned s0 = nf.x;
  int deg = (int)nf.y;
  float ad = adst[n];
  int cl = lane & 7;              // feature slot: floats 4*cl..4*cl+3
  const char* hbase = (const char*)h2b + 8*cl;
  float4 acc = make_float4(0,0,0,0);
  float den = 0.f;

  if (deg <= 64){
    unsigned boff = 0;
    float e = 0.f;
    if (lane < deg){
      int idx = csr_src[s0 + lane];
      boff = ((unsigned)idx) << 6;          // 64 B bf16 row
      e = __expf(leaky02(asrc[idx] + ad));
    }
    st[w][lane] = make_uint2(__float_as_uint(e), boff);
    __builtin_amdgcn_wave_barrier();
    int g8 = lane >> 3;
    const uint2* sp = &st[w][g8];
    #pragma unroll 4
    for (int i = 0; i < deg; i += 8){
      uint2 p = sp[i];
      float es = __uint_as_float(p.x);
      uint2 hb = *(const uint2*)(hbase + p.y);
      acc.x += es*bf_lo(hb.x); acc.y += es*bf_hi(hb.x);
      acc.z += es*bf_lo(hb.y); acc.w += es*bf_hi(hb.y);
      den += es;
    }
    #pragma unroll
    for (int mm = 8; mm <= 32; mm <<= 1){
      acc.x += __shfl_xor(acc.x, mm); acc.y += __shfl_xor(acc.y, mm);
      acc.z += __shfl_xor(acc.z, mm); acc.w += __shfl_xor(acc.w, mm);
      den   += __shfl_xor(den, mm);
    }
  } else {
    for (int i = 0; i < deg; ++i){
      int s = csr_src[s0 + i];
      float ev = __expf(leaky02(asrc[s] + ad));
      uint2 hb = *(const uint2*)(hbase + (((unsigned)s) << 6));
      acc.x += ev*bf_lo(hb.x); acc.y += ev*bf_hi(hb.x);
      acc.z += ev*bf_lo(hb.y); acc.w += ev*bf_hi(hb.y);
      den += ev;
    }
  }
  if (lane < 8){
    float inv = 1.f/(den + 1e-16f);
    float4 bv = ((const float4*)b2)[cl];
    float4 o;
    o.x = acc.x*inv + bv.x; o.y = acc.y*inv + bv.y;
    o.z = acc.z*inv + bv.z; o.w = acc.w*inv + bv.w;
    *(float4*)(hout + (size_t)n*32 + 4*cl) = o;
  }
}

// ---------------- pool: 8 blocks per graph -> deterministic partials + gcnt ------------
__global__ __launch_bounds__(256) void k_pool(const int* __restrict__ batch,
    const float* __restrict__ hout, float* __restrict__ gpart, int* __restrict__ gcnt)
{
  int g = blockIdx.x >> 3, sub = blockIdx.x & 7;
  int a = 0, b = N_NODES;
  while (a < b){ int mid = (a+b)>>1; if (batch[mid] < g) a = mid+1; else b = mid; }
  int lo = a;
  b = N_NODES;
  while (a < b){ int mid = (a+b)>>1; if (batch[mid] < g+1) a = mid+1; else b = mid; }
  int hi = a;
  if (sub == 0 && threadIdx.x == 0) gcnt[g] = hi - lo;
  int c = threadIdx.x & 31, rg = threadIdx.x >> 5;   // 8 row groups
  float s = 0.f;
  for (int r = lo + sub*8 + rg; r < hi; r += 64) s += hout[(size_t)r*32 + c];
  __shared__ float red[8][32];
  red[rg][c] = s;
  __syncthreads();
  if (rg == 0){
    float t = 0.f;
    #pragma unroll
    for (int k = 0; k < 8; ++k) t += red[k][c];
    gpart[(size_t)blockIdx.x*32 + c] = t;
  }
}

// ---------------- final: sum partials (float4), mean, MLP (64 graphs, 1 block) ---------
__global__ void k_final(const int* __restrict__ gcnt, const float* __restrict__ gpart,
    const float* __restrict__ l1w, const float* __restrict__ l1b,
    const float* __restrict__ l2w, const float* __restrict__ l2b, float* __restrict__ out)
{
  int t = threadIdx.x;
  if (t >= NG) return;
  float cinv = 1.f / fmaxf((float)gcnt[t], 1.0f);
  float4 gs[8];
  #pragma unroll
  for (int q = 0; q < 8; ++q) gs[q] = make_float4(0,0,0,0);
  #pragma unroll
  for (int p = 0; p < 8; ++p){
    const float4* pp = (const float4*)(gpart + (size_t)(t*8 + p)*32);
    #pragma unroll
    for (int q = 0; q < 8; ++q){
      float4 v = pp[q];
      gs[q].x += v.x; gs[q].y += v.y; gs[q].z += v.z; gs[q].w += v.w;
    }
  }
  float g[32];
  #pragma unroll
  for (int q = 0; q < 8; ++q){
    g[4*q]   = gs[q].x * cinv; g[4*q+1] = gs[q].y * cinv;
    g[4*q+2] = gs[q].z * cinv; g[4*q+3] = gs[q].w * cinv;
  }
  float o = l2b[0];
  #pragma unroll
  for (int k = 0; k < 16; ++k){
    float hv = l1b[k];
    #pragma unroll
    for (int j = 0; j < 32; ++j) hv += g[j]*l1w[j*16 + k];
    o += eluf(hv) * l2w[k];
  }
  out[t] = o;
}

extern "C" void kernel_launch(void* const* d_in, const int* in_sizes, int n_in,
                              void* d_out, int out_size, void* d_ws, size_t ws_size,
                              hipStream_t stream) {
  const float* x     = (const float*)d_in[0];
  const int*   ei    = (const int*)  d_in[1];
  const int*   batch = (const int*)  d_in[2];
  const float* W1    = (const float*)d_in[3];
  const float* attS1 = (const float*)d_in[4];
  const float* attD1 = (const float*)d_in[5];
  const float* b1    = (const float*)d_in[6];
  const float* W2    = (const float*)d_in[7];
  const float* attS2 = (const float*)d_in[8];
  const float* attD2 = (const float*)d_in[9];
  const float* b2    = (const float*)d_in[10];
  const float* l1w   = (const float*)d_in[11];
  const float* l1b   = (const float*)d_in[12];
  const float* l2w   = (const float*)d_in[13];
  const float* l2b   = (const float*)d_in[14];
  float* out = (float*)d_out;

  char* w = (char*)d_ws;
  auto alloc = [&](size_t elems) -> void* {
    void* p = (void*)w;
    w += ((elems*4 + 255)/256)*256;
    return p;
  };
  unsigned* gcur    = (unsigned*)alloc(NBUCK);
  unsigned* staging = (unsigned*)alloc((size_t)NBUCK*CAP);
  int*      csr_src = (int*)     alloc((size_t)NBUCK*CAP);
  uint2*    nfo     = (uint2*)   alloc((size_t)N_NODES*2);
  unsigned* wt1g  = (unsigned*)alloc(128*64);               // bf16 W1^T [128c][128k]
  unsigned* wt2g  = (unsigned*)alloc(32*64);                // bf16 W2^T [32c][128k]
  unsigned* h1f   = (unsigned*)alloc((size_t)N_NODES*32);   // fp8-packed [N,128]
  float*    asrc1 = (float*)alloc((size_t)N_NODES*4);
  float*    adst1 = (float*)alloc((size_t)N_NODES*4);
  unsigned* helu_b= (unsigned*)alloc((size_t)N_NODES*64);   // bf16-packed [N,128]
  unsigned* h2b   = (unsigned*)alloc((size_t)N_NODES*16);   // bf16-packed [N,32]
  float*    asrc2 = (float*)alloc(N_NODES);
  float*    adst2 = (float*)alloc(N_NODES);
  float*    hout  = (float*)alloc((size_t)N_NODES*32);
  float*    gpart = (float*)alloc(NG*8*32);
  int*      gcnt  = (int*)alloc(NG);

  hipMemsetAsync(gcur, 0, NBUCK*4, stream);

  k_partA<<<NCHUNK + 160, 256, 0, stream>>>(ei, gcur, staging, W1, W2, wt1g, wt2g);
  k_cg   <<<NBUCK + GB1, 256, 0, stream>>>(gcur, staging, nfo, csr_src,
                                           x, wt1g, attS1, attD1, h1f, asrc1, adst1);
  k_conv1<<<(N_NODES + 3)/4, 256, 0, stream>>>(nfo, csr_src, h1f, asrc1, adst1, b1, helu_b);
  k_gemm2<<<(N_NODES + 63)/64, 256, 0, stream>>>(helu_b, wt2g, attS2, attD2, h2b, asrc2, adst2);
  k_conv2<<<(N_NODES + 3)/4, 256, 0, stream>>>(nfo, csr_src, h2b, asrc2, adst2, b2, hout);
  k_pool <<<NG*8, 256, 0, stream>>>(batch, hout, gpart, gcnt);
  k_final<<<1, 64, 0, stream>>>(gcnt, gpart, l1w, l1b, l2w, l2b, out);
}